// Round 9
// baseline (419.532 us; speedup 1.0000x reference)
//
#include <hip/hip_runtime.h>

static constexpr int NN = 100000;   // nodes
static constexpr int NE = 1600000;  // edges
static constexpr int C  = 128;      // feature dim
static constexpr int OC = 10;       // output classes
static constexpr int NG = 512;      // graphs

// Bucketed CSR build parameters
static constexpr int BSH  = 9;                         // 512 nodes per bucket
static constexpr int BNW  = 1 << BSH;                  // 512
static constexpr int BK   = (NN + BNW - 1) / BNW;      // 196 buckets
static constexpr int BCAP = 12288;                     // slab capacity (avg ~8163)
static constexpr int EPB  = 8192;                      // edges per binA block
static constexpr int ABLK = (NE + EPB - 1) / EPB;      // 196

typedef unsigned short u16;
typedef __attribute__((ext_vector_type(8))) short short8;   // 8 bf16 = 16B
typedef __attribute__((ext_vector_type(8))) short bf16x8;   // MFMA A/B frag
typedef __attribute__((ext_vector_type(4))) float f32x4;    // MFMA C/D frag

__device__ __forceinline__ float bf2f(u16 u) {
    union { float f; unsigned int u32; } v; v.u32 = ((unsigned int)u) << 16; return v.f;
}
__device__ __forceinline__ u16 f2bf(float f) {
    union { float f; unsigned int u; } v; v.f = f;
    unsigned int u = v.u;
    unsigned int r = u + 0x7FFF + ((u >> 16) & 1);   // RNE
    return (u16)(r >> 16);
}

// ---------------------------------------------------------------------------
// Phase A: bin edges into BK buckets by dst>>BSH (L2-local slab writes).
// ---------------------------------------------------------------------------
__global__ __launch_bounds__(256) void k_binA(const int* __restrict__ src,
                                              const int* __restrict__ dst,
                                              int* __restrict__ gcnt,
                                              int* __restrict__ buck) {
    __shared__ int cnt[BK];
    __shared__ int curs[BK];
    int tid = threadIdx.x;
    for (int i = tid; i < BK; i += 256) cnt[i] = 0;
    __syncthreads();
    int e0 = blockIdx.x * EPB;
    for (int i = tid; i < EPB; i += 256) {
        int e = e0 + i;
        if (e < NE) atomicAdd(&cnt[dst[e] >> BSH], 1);
    }
    __syncthreads();
    for (int i = tid; i < BK; i += 256) {
        int c = cnt[i];
        int gb = (c > 0) ? atomicAdd(&gcnt[i], c) : 0;
        curs[i] = i * BCAP + gb;
    }
    __syncthreads();
    for (int i = tid; i < EPB; i += 256) {
        int e = e0 + i;
        if (e < NE) {
            int d = dst[e];
            int b = d >> BSH;
            int p = atomicAdd(&curs[b], 1);
            if (p < (b + 1) * BCAP)
                buck[p] = (src[e] << BSH) | (d & (BNW - 1));
        }
    }
}

// ---------------------------------------------------------------------------
// Exclusive scan of bucket counts -> per-bucket CSR base.  Also rp[NN]=NE.
// ---------------------------------------------------------------------------
__global__ void k_binscan(const int* __restrict__ gcnt, int* __restrict__ csrbase,
                          int* __restrict__ rp) {
    __shared__ int buf[256];
    int tid = threadIdx.x;
    int v = (tid < BK) ? gcnt[tid] : 0;
    buf[tid] = v;
    __syncthreads();
    for (int off = 1; off < 256; off <<= 1) {
        int t = (tid >= off) ? buf[tid - off] : 0;
        __syncthreads();
        buf[tid] += t;
        __syncthreads();
    }
    if (tid < BK) csrbase[tid] = buf[tid] - v;
    if (tid == 0) rp[NN] = NE;
}

// ---------------------------------------------------------------------------
// Phase B: one block per bucket.  LDS histogram over the bucket's 512 nodes,
// LDS scan -> rp slice, then LDS-cursor scatter into the bucket's contiguous
// CSR window (single block -> L2-local writes).
// ---------------------------------------------------------------------------
__global__ __launch_bounds__(BNW) void k_binB(const int* __restrict__ gcnt,
                                              const int* __restrict__ csrbase,
                                              const int* __restrict__ buck,
                                              int* __restrict__ rp,
                                              int* __restrict__ csr) {
    int b = blockIdx.x;
    int tid = threadIdx.x;
    __shared__ int hist[BNW];     // histogram, then cursor
    __shared__ int scanbuf[BNW];
    int n = gcnt[b];
    if (n > BCAP) n = BCAP;
    int base = csrbase[b];
    const int* bb = buck + (size_t)b * BCAP;

    hist[tid] = 0;
    __syncthreads();
    for (int i = tid; i < n; i += BNW) atomicAdd(&hist[bb[i] & (BNW - 1)], 1);
    __syncthreads();

    int v = hist[tid];
    scanbuf[tid] = v;
    __syncthreads();
    for (int off = 1; off < BNW; off <<= 1) {
        int t = (tid >= off) ? scanbuf[tid - off] : 0;
        __syncthreads();
        scanbuf[tid] += t;
        __syncthreads();
    }
    int excl = scanbuf[tid] - v;
    int node = (b << BSH) + tid;
    if (node < NN) rp[node] = base + excl;
    __syncthreads();
    hist[tid] = base + excl;      // cursor
    __syncthreads();
    for (int i = tid; i < n; i += BNW) {
        int en = bb[i];
        int p = atomicAdd(&hist[en & (BNW - 1)], 1);
        csr[p] = en >> BSH;
    }
}

// ---------------------------------------------------------------------------
// f32 -> bf16 conversion (8 elems/thread)
// ---------------------------------------------------------------------------
__global__ void k_cvt_bf16(const float* __restrict__ in, u16* __restrict__ out) {
    int i = blockIdx.x * blockDim.x + threadIdx.x;
    size_t base = (size_t)i * 8;
    if (base >= (size_t)NN * C) return;
    float4 a = *reinterpret_cast<const float4*>(in + base);
    float4 b = *reinterpret_cast<const float4*>(in + base + 4);
    u16 o[8] = { f2bf(a.x), f2bf(a.y), f2bf(a.z), f2bf(a.w),
                 f2bf(b.x), f2bf(b.y), f2bf(b.z), f2bf(b.w) };
    *reinterpret_cast<short8*>(out + base) = *reinterpret_cast<const short8*>(o);
}

// ---------------------------------------------------------------------------
// Pack [W_rel; W_root] (256x128 f32) into per-lane MFMA B-fragment order, bf16.
// ---------------------------------------------------------------------------
__global__ void k_pack_w(const float* __restrict__ W_rel,
                         const float* __restrict__ W_root,
                         u16* __restrict__ Bp) {
    int t = blockIdx.x * blockDim.x + threadIdx.x;   // 0..4095
    if (t >= 4096) return;
    int lane = t & 63;
    int nfrag = (t >> 6) & 7;
    int kk = t >> 9;
    int col = nfrag * 16 + (lane & 15);
    int k0 = kk * 32 + (lane >> 4) * 8;
    u16 vals[8];
#pragma unroll
    for (int j = 0; j < 8; ++j) {
        int k = k0 + j;
        float w = (k < C) ? W_rel[k * C + col] : W_root[(k - C) * C + col];
        vals[j] = f2bf(w);
    }
    *reinterpret_cast<short8*>(Bp + (size_t)t * 8) = *reinterpret_cast<const short8*>(vals);
}

// ---------------------------------------------------------------------------
// Gather-aggregate (bf16): agg[i] = sum_{j in in(i)} h[j].  16 lanes/node.
// Edge loop unrolled x8: 8 independent index + feature loads in flight per
// thread to hide L2/L3 latency.
// ---------------------------------------------------------------------------
__global__ void k_gather(const u16* __restrict__ h, const int* __restrict__ rp,
                         const int* __restrict__ csr, u16* __restrict__ agg) {
    int t = blockIdx.x * blockDim.x + threadIdx.x;
    int node = t >> 4;
    if (node >= NN) return;
    int seg = (t & 15) * 8;   // element offset within row
    int beg = rp[node], end = rp[node + 1];
    float acc[8] = {};
    int j = beg;
    for (; j + 8 <= end; j += 8) {
        int s0 = csr[j];
        int s1 = csr[j + 1];
        int s2 = csr[j + 2];
        int s3 = csr[j + 3];
        int s4 = csr[j + 4];
        int s5 = csr[j + 5];
        int s6 = csr[j + 6];
        int s7 = csr[j + 7];
        short8 v0 = *reinterpret_cast<const short8*>(h + (size_t)s0 * C + seg);
        short8 v1 = *reinterpret_cast<const short8*>(h + (size_t)s1 * C + seg);
        short8 v2 = *reinterpret_cast<const short8*>(h + (size_t)s2 * C + seg);
        short8 v3 = *reinterpret_cast<const short8*>(h + (size_t)s3 * C + seg);
        short8 v4 = *reinterpret_cast<const short8*>(h + (size_t)s4 * C + seg);
        short8 v5 = *reinterpret_cast<const short8*>(h + (size_t)s5 * C + seg);
        short8 v6 = *reinterpret_cast<const short8*>(h + (size_t)s6 * C + seg);
        short8 v7 = *reinterpret_cast<const short8*>(h + (size_t)s7 * C + seg);
#pragma unroll
        for (int q = 0; q < 8; ++q) {
            acc[q] += bf2f((u16)v0[q]);
            acc[q] += bf2f((u16)v1[q]);
            acc[q] += bf2f((u16)v2[q]);
            acc[q] += bf2f((u16)v3[q]);
            acc[q] += bf2f((u16)v4[q]);
            acc[q] += bf2f((u16)v5[q]);
            acc[q] += bf2f((u16)v6[q]);
            acc[q] += bf2f((u16)v7[q]);
        }
    }
    for (; j < end; ++j) {
        int s = csr[j];
        short8 v = *reinterpret_cast<const short8*>(h + (size_t)s * C + seg);
#pragma unroll
        for (int q = 0; q < 8; ++q) acc[q] += bf2f((u16)v[q]);
    }
    u16 o[8];
#pragma unroll
    for (int q = 0; q < 8; ++q) o[q] = f2bf(acc[q]);
    *reinterpret_cast<short8*>(agg + (size_t)node * C + seg) = *reinterpret_cast<const short8*>(o);
}

// ---------------------------------------------------------------------------
// MFMA transform: out = [relu]( [agg|h] @ [W_rel;W_root] + b ), bf16 in/out.
// Block = 4 waves x 32 rows = 128 nodes; each wave computes 2 A-frag sets per
// B-frag load (halves B traffic per row, doubles MFMA per load).
// In-place safe: a garbage/clamped A row only pollutes the D row of that
// same (invalid) index, which is never written.
// ---------------------------------------------------------------------------
template <bool RELU>
__global__ __launch_bounds__(256) void k_transform_mfma(
    const u16* __restrict__ agg, const u16* __restrict__ h,
    const u16* __restrict__ Bp, const float* __restrict__ bias,
    u16* __restrict__ out) {
    int wave = threadIdx.x >> 6;
    int lane = threadIdx.x & 63;
    int row0 = blockIdx.x * 128 + wave * 32;
    int r0 = row0 + (lane & 15);
    int r1 = r0 + 16;
    int r0c = r0 < NN ? r0 : NN - 1;
    int r1c = r1 < NN ? r1 : NN - 1;
    int koff = (lane >> 4) * 8;

    f32x4 acc0[8] = {};
    f32x4 acc1[8] = {};
#pragma unroll
    for (int kk = 0; kk < 8; ++kk) {
        const u16* srcb = (kk < 4) ? agg : h;
        int kbase = (kk & 3) * 32 + koff;
        bf16x8 a0 = *reinterpret_cast<const bf16x8*>(srcb + (size_t)r0c * C + kbase);
        bf16x8 a1 = *reinterpret_cast<const bf16x8*>(srcb + (size_t)r1c * C + kbase);
        const u16* bp = Bp + ((size_t)kk * 8 * 64 + lane) * 8;
#pragma unroll
        for (int n = 0; n < 8; ++n) {
            bf16x8 bfr = *reinterpret_cast<const bf16x8*>(bp + (size_t)n * 64 * 8);
            acc0[n] = __builtin_amdgcn_mfma_f32_16x16x32_bf16(a0, bfr, acc0[n], 0, 0, 0);
            acc1[n] = __builtin_amdgcn_mfma_f32_16x16x32_bf16(a1, bfr, acc1[n], 0, 0, 0);
        }
    }
    int colbase = lane & 15;
    int rowe = row0 + (lane >> 4) * 4;
#pragma unroll
    for (int n = 0; n < 8; ++n) {
        int col = n * 16 + colbase;
        float bb = bias[col];
#pragma unroll
        for (int r = 0; r < 4; ++r) {
            int ro = rowe + r;
            if (ro < NN) {
                float v = acc0[n][r] + bb;
                if (RELU) v = fmaxf(v, 0.0f);
                out[(size_t)ro * C + col] = f2bf(v);
            }
            int ro1 = ro + 16;
            if (ro1 < NN) {
                float v = acc1[n][r] + bb;
                if (RELU) v = fmaxf(v, 0.0f);
                out[(size_t)ro1 * C + col] = f2bf(v);
            }
        }
    }
}

// ---------------------------------------------------------------------------
// Graph boundaries via binary search (batch is sorted), then fused pool+linear.
// ---------------------------------------------------------------------------
__global__ void k_gbounds(const int* __restrict__ batch, int* __restrict__ gstart) {
    int g = blockIdx.x * blockDim.x + threadIdx.x;
    if (g > NG) return;
    int lo = 0, hi = NN;
    while (lo < hi) { int mid = (lo + hi) >> 1; if (batch[mid] < g) lo = mid + 1; else hi = mid; }
    gstart[g] = lo;
}

// ---------------------------------------------------------------------------
// Fused mean-pool + final linear.  Block = 256 threads = 16 row-slots x 16
// col-segments; coalesced short8 strided loads, LDS tree-reduce, 128x10 GEMV.
// ---------------------------------------------------------------------------
__global__ __launch_bounds__(256) void k_pool_final(
    const u16* __restrict__ h, const int* __restrict__ gstart,
    const float* __restrict__ W_lin, const float* __restrict__ b_lin,
    float* __restrict__ out) {
    int g = blockIdx.x;
    int rowslot = threadIdx.x >> 4;      // 0..15
    int seg = threadIdx.x & 15;          // 0..15 (8 cols each)
    int s = gstart[g], e = gstart[g + 1];

    float acc[8] = {};
    for (int i = s + rowslot; i < e; i += 16) {
        short8 v = *reinterpret_cast<const short8*>(h + (size_t)i * C + seg * 8);
#pragma unroll
        for (int q = 0; q < 8; ++q) acc[q] += bf2f((u16)v[q]);
    }

    __shared__ float red[16][C];         // 8 KB
#pragma unroll
    for (int q = 0; q < 8; ++q) red[rowslot][seg * 8 + q] = acc[q];
    __syncthreads();

    __shared__ float sp[C];
    if (threadIdx.x < C) {
        float sum = 0.0f;
#pragma unroll
        for (int r = 0; r < 16; ++r) sum += red[r][threadIdx.x];
        float cnt = (float)max(e - s, 1);
        sp[threadIdx.x] = sum / cnt;
    }
    __syncthreads();
    if (threadIdx.x < OC) {
        float o = b_lin[threadIdx.x];
#pragma unroll 8
        for (int k = 0; k < C; ++k) o += sp[k] * W_lin[k * OC + threadIdx.x];
        out[g * OC + threadIdx.x] = o;
    }
}

extern "C" void kernel_launch(void* const* d_in, const int* in_sizes, int n_in,
                              void* d_out, int out_size, void* d_ws, size_t ws_size,
                              hipStream_t stream) {
    const float* x       = (const float*)d_in[0];
    const int*   eidx    = (const int*)d_in[1];
    const int*   batch   = (const int*)d_in[2];
    const float* W1_rel  = (const float*)d_in[3];
    const float* b1      = (const float*)d_in[4];
    const float* W1_root = (const float*)d_in[5];
    const float* W2_rel  = (const float*)d_in[6];
    const float* b2      = (const float*)d_in[7];
    const float* W2_root = (const float*)d_in[8];
    const float* W3_rel  = (const float*)d_in[9];
    const float* b3      = (const float*)d_in[10];
    const float* W3_root = (const float*)d_in[11];
    const float* W_lin   = (const float*)d_in[12];
    const float* b_lin   = (const float*)d_in[13];
    float* out = (float*)d_out;

    const int* src = eidx;
    const int* dst = eidx + NE;

    // Workspace layout
    u16* xb   = (u16*)d_ws;                       // NN*C bf16
    u16* hb   = xb + (size_t)NN * C;              // NN*C bf16
    u16* aggb = hb + (size_t)NN * C;              // NN*C bf16
    u16* Bp   = aggb + (size_t)NN * C;            // 3 * 32768 bf16
    int* rp      = (int*)(Bp + 3 * 32768);        // NN+1
    int* csr     = rp + NN + 1;                   // NE
    int* buck    = csr + NE;                      // BK*BCAP
    int* gcnt    = buck + (size_t)BK * BCAP;      // BK
    int* csrbase = gcnt + BK;                     // BK
    int* gstart  = csrbase + BK;                  // NG+1

    const int gb = (NN * 16 + 255) / 256;         // gather blocks (16 lanes/node)
    const int tb = (NN + 127) / 128;              // transform blocks (128 rows)
    const int cvtb = ((NN * C / 8) + 255) / 256;

    // ---- Bucketed CSR build (shared by all 3 layers) ----
    hipMemsetAsync(gcnt, 0, BK * sizeof(int), stream);
    k_binA<<<ABLK, 256, 0, stream>>>(src, dst, gcnt, buck);
    k_binscan<<<1, 256, 0, stream>>>(gcnt, csrbase, rp);
    k_binB<<<BK, BNW, 0, stream>>>(gcnt, csrbase, buck, rp, csr);

    // ---- Precompute: x->bf16, packed weights, graph bounds ----
    k_cvt_bf16<<<cvtb, 256, 0, stream>>>(x, xb);
    k_pack_w<<<16, 256, 0, stream>>>(W1_rel, W1_root, Bp);
    k_pack_w<<<16, 256, 0, stream>>>(W2_rel, W2_root, Bp + 32768);
    k_pack_w<<<16, 256, 0, stream>>>(W3_rel, W3_root, Bp + 2 * 32768);
    k_gbounds<<<3, 256, 0, stream>>>(batch, gstart);

    // ---- Layer 1 ----
    k_gather<<<gb, 256, 0, stream>>>(xb, rp, csr, aggb);
    k_transform_mfma<true><<<tb, 256, 0, stream>>>(aggb, xb, Bp, b1, hb);

    // ---- Layer 2 (in-place) ----
    k_gather<<<gb, 256, 0, stream>>>(hb, rp, csr, aggb);
    k_transform_mfma<true><<<tb, 256, 0, stream>>>(aggb, hb, Bp + 32768, b2, hb);

    // ---- Layer 3 (no relu, in-place) ----
    k_gather<<<gb, 256, 0, stream>>>(hb, rp, csr, aggb);
    k_transform_mfma<false><<<tb, 256, 0, stream>>>(aggb, hb, Bp + 2 * 32768, b3, hb);

    // ---- Fused pool + final linear ----
    k_pool_final<<<NG, 256, 0, stream>>>(hb, gstart, W_lin, b_lin, out);
}

// Round 10
// 343.199 us; speedup vs baseline: 1.2224x; 1.2224x over previous
//
#include <hip/hip_runtime.h>

static constexpr int NN = 100000;   // nodes
static constexpr int NE = 1600000;  // edges
static constexpr int C  = 128;      // feature dim
static constexpr int OC = 10;       // output classes
static constexpr int NG = 512;      // graphs

// Bucketed CSR build parameters
static constexpr int BSH  = 9;                         // 512 nodes per bucket
static constexpr int BNW  = 1 << BSH;                  // 512
static constexpr int BK   = (NN + BNW - 1) / BNW;      // 196 buckets
static constexpr int BCAP = 12288;                     // slab capacity (avg ~8163)
static constexpr int EPB  = 8192;                      // edges per binA block
static constexpr int ABLK = (NE + EPB - 1) / EPB;      // 196

static constexpr int TSTRIDE = 132;                    // LDS tile row stride (u16)

typedef unsigned short u16;
typedef __attribute__((ext_vector_type(8))) short short8;   // 8 bf16 = 16B
typedef __attribute__((ext_vector_type(8))) short bf16x8;   // MFMA A/B frag
typedef __attribute__((ext_vector_type(4))) float f32x4;    // MFMA C/D frag

__device__ __forceinline__ float bf2f(u16 u) {
    union { float f; unsigned int u32; } v; v.u32 = ((unsigned int)u) << 16; return v.f;
}
__device__ __forceinline__ u16 f2bf(float f) {
    union { float f; unsigned int u; } v; v.f = f;
    unsigned int u = v.u;
    unsigned int r = u + 0x7FFF + ((u >> 16) & 1);   // RNE
    return (u16)(r >> 16);
}

// ---------------------------------------------------------------------------
// Phase A: bin edges into BK buckets by dst>>BSH (L2-local slab writes).
// ---------------------------------------------------------------------------
__global__ __launch_bounds__(256) void k_binA(const int* __restrict__ src,
                                              const int* __restrict__ dst,
                                              int* __restrict__ gcnt,
                                              int* __restrict__ buck) {
    __shared__ int cnt[BK];
    __shared__ int curs[BK];
    int tid = threadIdx.x;
    for (int i = tid; i < BK; i += 256) cnt[i] = 0;
    __syncthreads();
    int e0 = blockIdx.x * EPB;
    for (int i = tid; i < EPB; i += 256) {
        int e = e0 + i;
        if (e < NE) atomicAdd(&cnt[dst[e] >> BSH], 1);
    }
    __syncthreads();
    for (int i = tid; i < BK; i += 256) {
        int c = cnt[i];
        int gb = (c > 0) ? atomicAdd(&gcnt[i], c) : 0;
        curs[i] = i * BCAP + gb;
    }
    __syncthreads();
    for (int i = tid; i < EPB; i += 256) {
        int e = e0 + i;
        if (e < NE) {
            int d = dst[e];
            int b = d >> BSH;
            int p = atomicAdd(&curs[b], 1);
            if (p < (b + 1) * BCAP)
                buck[p] = (src[e] << BSH) | (d & (BNW - 1));
        }
    }
}

// ---------------------------------------------------------------------------
// Exclusive scan of bucket counts -> per-bucket CSR base.  Also rp[NN]=NE.
// ---------------------------------------------------------------------------
__global__ void k_binscan(const int* __restrict__ gcnt, int* __restrict__ csrbase,
                          int* __restrict__ rp) {
    __shared__ int buf[256];
    int tid = threadIdx.x;
    int v = (tid < BK) ? gcnt[tid] : 0;
    buf[tid] = v;
    __syncthreads();
    for (int off = 1; off < 256; off <<= 1) {
        int t = (tid >= off) ? buf[tid - off] : 0;
        __syncthreads();
        buf[tid] += t;
        __syncthreads();
    }
    if (tid < BK) csrbase[tid] = buf[tid] - v;
    if (tid == 0) rp[NN] = NE;
}

// ---------------------------------------------------------------------------
// Phase B: one block per bucket.  LDS histogram over the bucket's 512 nodes,
// LDS scan -> rp slice, then LDS-cursor scatter into the bucket's contiguous
// CSR window (single block -> L2-local writes).
// ---------------------------------------------------------------------------
__global__ __launch_bounds__(BNW) void k_binB(const int* __restrict__ gcnt,
                                              const int* __restrict__ csrbase,
                                              const int* __restrict__ buck,
                                              int* __restrict__ rp,
                                              int* __restrict__ csr) {
    int b = blockIdx.x;
    int tid = threadIdx.x;
    __shared__ int hist[BNW];     // histogram, then cursor
    __shared__ int scanbuf[BNW];
    int n = gcnt[b];
    if (n > BCAP) n = BCAP;
    int base = csrbase[b];
    const int* bb = buck + (size_t)b * BCAP;

    hist[tid] = 0;
    __syncthreads();
    for (int i = tid; i < n; i += BNW) atomicAdd(&hist[bb[i] & (BNW - 1)], 1);
    __syncthreads();

    int v = hist[tid];
    scanbuf[tid] = v;
    __syncthreads();
    for (int off = 1; off < BNW; off <<= 1) {
        int t = (tid >= off) ? scanbuf[tid - off] : 0;
        __syncthreads();
        scanbuf[tid] += t;
        __syncthreads();
    }
    int excl = scanbuf[tid] - v;
    int node = (b << BSH) + tid;
    if (node < NN) rp[node] = base + excl;
    __syncthreads();
    hist[tid] = base + excl;      // cursor
    __syncthreads();
    for (int i = tid; i < n; i += BNW) {
        int en = bb[i];
        int p = atomicAdd(&hist[en & (BNW - 1)], 1);
        csr[p] = en >> BSH;
    }
}

// ---------------------------------------------------------------------------
// f32 -> bf16 conversion (8 elems/thread)
// ---------------------------------------------------------------------------
__global__ void k_cvt_bf16(const float* __restrict__ in, u16* __restrict__ out) {
    int i = blockIdx.x * blockDim.x + threadIdx.x;
    size_t base = (size_t)i * 8;
    if (base >= (size_t)NN * C) return;
    float4 a = *reinterpret_cast<const float4*>(in + base);
    float4 b = *reinterpret_cast<const float4*>(in + base + 4);
    u16 o[8] = { f2bf(a.x), f2bf(a.y), f2bf(a.z), f2bf(a.w),
                 f2bf(b.x), f2bf(b.y), f2bf(b.z), f2bf(b.w) };
    *reinterpret_cast<short8*>(out + base) = *reinterpret_cast<const short8*>(o);
}

// ---------------------------------------------------------------------------
// Pack [W_rel; W_root] (256x128 f32) into per-lane MFMA B-fragment order, bf16.
// ---------------------------------------------------------------------------
__global__ void k_pack_w(const float* __restrict__ W_rel,
                         const float* __restrict__ W_root,
                         u16* __restrict__ Bp) {
    int t = blockIdx.x * blockDim.x + threadIdx.x;   // 0..4095
    if (t >= 4096) return;
    int lane = t & 63;
    int nfrag = (t >> 6) & 7;
    int kk = t >> 9;
    int col = nfrag * 16 + (lane & 15);
    int k0 = kk * 32 + (lane >> 4) * 8;
    u16 vals[8];
#pragma unroll
    for (int j = 0; j < 8; ++j) {
        int k = k0 + j;
        float w = (k < C) ? W_rel[k * C + col] : W_root[(k - C) * C + col];
        vals[j] = f2bf(w);
    }
    *reinterpret_cast<short8*>(Bp + (size_t)t * 8) = *reinterpret_cast<const short8*>(vals);
}

// ---------------------------------------------------------------------------
// Gather-aggregate (bf16): agg[i] = sum_{j in in(i)} h[j].  16 lanes/node.
// Edge loop unrolled x4 (4 loads in flight per thread) -- the measured
// sweet spot (x8 regressed occupancy, round 9).
// ---------------------------------------------------------------------------
__global__ void k_gather(const u16* __restrict__ h, const int* __restrict__ rp,
                         const int* __restrict__ csr, u16* __restrict__ agg) {
    int t = blockIdx.x * blockDim.x + threadIdx.x;
    int node = t >> 4;
    if (node >= NN) return;
    int seg = (t & 15) * 8;   // element offset within row
    int beg = rp[node], end = rp[node + 1];
    float acc[8] = {};
    int j = beg;
    for (; j + 4 <= end; j += 4) {
        int s0 = csr[j];
        int s1 = csr[j + 1];
        int s2 = csr[j + 2];
        int s3 = csr[j + 3];
        short8 v0 = *reinterpret_cast<const short8*>(h + (size_t)s0 * C + seg);
        short8 v1 = *reinterpret_cast<const short8*>(h + (size_t)s1 * C + seg);
        short8 v2 = *reinterpret_cast<const short8*>(h + (size_t)s2 * C + seg);
        short8 v3 = *reinterpret_cast<const short8*>(h + (size_t)s3 * C + seg);
#pragma unroll
        for (int q = 0; q < 8; ++q) {
            acc[q] += bf2f((u16)v0[q]);
            acc[q] += bf2f((u16)v1[q]);
            acc[q] += bf2f((u16)v2[q]);
            acc[q] += bf2f((u16)v3[q]);
        }
    }
    for (; j < end; ++j) {
        int s = csr[j];
        short8 v = *reinterpret_cast<const short8*>(h + (size_t)s * C + seg);
#pragma unroll
        for (int q = 0; q < 8; ++q) acc[q] += bf2f((u16)v[q]);
    }
    u16 o[8];
#pragma unroll
    for (int q = 0; q < 8; ++q) o[q] = f2bf(acc[q]);
    *reinterpret_cast<short8*>(agg + (size_t)node * C + seg) = *reinterpret_cast<const short8*>(o);
}

// ---------------------------------------------------------------------------
// MFMA transform: out = [relu]( [agg|h] @ [W_rel;W_root] + b ), bf16 in/out.
// Block = 4 waves x 16 rows = 64 nodes; wave computes 16 x 128.
// Epilogue stages the D-tile in LDS (row stride 132 u16 -> bank-clean) and
// streams it out as coalesced 16 B chunks instead of 32 scalar 2 B stores.
// Safe in-place (out == h): each block only reads/writes its own rows.
// ---------------------------------------------------------------------------
template <bool RELU>
__global__ __launch_bounds__(256) void k_transform_mfma(
    const u16* __restrict__ agg, const u16* __restrict__ h,
    const u16* __restrict__ Bp, const float* __restrict__ bias,
    u16* __restrict__ out) {
    __shared__ u16 tile[4][16 * TSTRIDE];   // 16.9 KB
    int wave = threadIdx.x >> 6;
    int lane = threadIdx.x & 63;
    int row0 = blockIdx.x * 64 + wave * 16;
    int arow = row0 + (lane & 15);
    int rclamp = arow < NN ? arow : NN - 1;
    int koff = (lane >> 4) * 8;

    f32x4 acc[8] = {};
#pragma unroll
    for (int kk = 0; kk < 8; ++kk) {
        bf16x8 a;
        if (kk < 4) {
            a = *reinterpret_cast<const bf16x8*>(agg + (size_t)rclamp * C + kk * 32 + koff);
        } else {
            a = *reinterpret_cast<const bf16x8*>(h + (size_t)rclamp * C + (kk - 4) * 32 + koff);
        }
        const u16* bp = Bp + ((size_t)kk * 8 * 64 + lane) * 8;
#pragma unroll
        for (int n = 0; n < 8; ++n) {
            bf16x8 b = *reinterpret_cast<const bf16x8*>(bp + (size_t)n * 64 * 8);
            acc[n] = __builtin_amdgcn_mfma_f32_16x16x32_bf16(a, b, acc[n], 0, 0, 0);
        }
    }

    // epilogue 1: bias+relu, D frag -> LDS tile (col = n*16+lane&15,
    // local row = (lane>>4)*4 + r)
    u16* T = tile[wave];
    int colbase = lane & 15;
    int rloc = (lane >> 4) * 4;
#pragma unroll
    for (int n = 0; n < 8; ++n) {
        int col = n * 16 + colbase;
        float bb = bias[col];
#pragma unroll
        for (int r = 0; r < 4; ++r) {
            float v = acc[n][r] + bb;
            if (RELU) v = fmaxf(v, 0.0f);
            T[(rloc + r) * TSTRIDE + col] = f2bf(v);
        }
    }
    __syncthreads();

    // epilogue 2: coalesced store, 4 x 16B chunks per lane
#pragma unroll
    for (int k = 0; k < 4; ++k) {
        int idx = k * 64 + lane;        // 0..255 chunk id in wave tile
        int lr = idx >> 4;              // local row 0..15
        int off = (idx & 15) * 8;       // u16 offset within row
        int ro = row0 + lr;
        if (ro < NN) {
            short8 v = *reinterpret_cast<const short8*>(&T[lr * TSTRIDE + off]);
            *reinterpret_cast<short8*>(out + (size_t)ro * C + off) = v;
        }
    }
}

// ---------------------------------------------------------------------------
// Graph boundaries via binary search (batch is sorted), then fused pool+linear.
// ---------------------------------------------------------------------------
__global__ void k_gbounds(const int* __restrict__ batch, int* __restrict__ gstart) {
    int g = blockIdx.x * blockDim.x + threadIdx.x;
    if (g > NG) return;
    int lo = 0, hi = NN;
    while (lo < hi) { int mid = (lo + hi) >> 1; if (batch[mid] < g) lo = mid + 1; else hi = mid; }
    gstart[g] = lo;
}

// ---------------------------------------------------------------------------
// Fused mean-pool + final linear.  Block = 256 threads = 16 row-slots x 16
// col-segments; coalesced short8 strided loads, LDS tree-reduce, 128x10 GEMV.
// ---------------------------------------------------------------------------
__global__ __launch_bounds__(256) void k_pool_final(
    const u16* __restrict__ h, const int* __restrict__ gstart,
    const float* __restrict__ W_lin, const float* __restrict__ b_lin,
    float* __restrict__ out) {
    int g = blockIdx.x;
    int rowslot = threadIdx.x >> 4;      // 0..15
    int seg = threadIdx.x & 15;          // 0..15 (8 cols each)
    int s = gstart[g], e = gstart[g + 1];

    float acc[8] = {};
    for (int i = s + rowslot; i < e; i += 16) {
        short8 v = *reinterpret_cast<const short8*>(h + (size_t)i * C + seg * 8);
#pragma unroll
        for (int q = 0; q < 8; ++q) acc[q] += bf2f((u16)v[q]);
    }

    __shared__ float red[16][C];         // 8 KB
#pragma unroll
    for (int q = 0; q < 8; ++q) red[rowslot][seg * 8 + q] = acc[q];
    __syncthreads();

    __shared__ float sp[C];
    if (threadIdx.x < C) {
        float sum = 0.0f;
#pragma unroll
        for (int r = 0; r < 16; ++r) sum += red[r][threadIdx.x];
        float cnt = (float)max(e - s, 1);
        sp[threadIdx.x] = sum / cnt;
    }
    __syncthreads();
    if (threadIdx.x < OC) {
        float o = b_lin[threadIdx.x];
#pragma unroll 8
        for (int k = 0; k < C; ++k) o += sp[k] * W_lin[k * OC + threadIdx.x];
        out[g * OC + threadIdx.x] = o;
    }
}

extern "C" void kernel_launch(void* const* d_in, const int* in_sizes, int n_in,
                              void* d_out, int out_size, void* d_ws, size_t ws_size,
                              hipStream_t stream) {
    const float* x       = (const float*)d_in[0];
    const int*   eidx    = (const int*)d_in[1];
    const int*   batch   = (const int*)d_in[2];
    const float* W1_rel  = (const float*)d_in[3];
    const float* b1      = (const float*)d_in[4];
    const float* W1_root = (const float*)d_in[5];
    const float* W2_rel  = (const float*)d_in[6];
    const float* b2      = (const float*)d_in[7];
    const float* W2_root = (const float*)d_in[8];
    const float* W3_rel  = (const float*)d_in[9];
    const float* b3      = (const float*)d_in[10];
    const float* W3_root = (const float*)d_in[11];
    const float* W_lin   = (const float*)d_in[12];
    const float* b_lin   = (const float*)d_in[13];
    float* out = (float*)d_out;

    const int* src = eidx;
    const int* dst = eidx + NE;

    // Workspace layout
    u16* xb   = (u16*)d_ws;                       // NN*C bf16
    u16* hb   = xb + (size_t)NN * C;              // NN*C bf16
    u16* aggb = hb + (size_t)NN * C;              // NN*C bf16
    u16* Bp   = aggb + (size_t)NN * C;            // 3 * 32768 bf16
    int* rp      = (int*)(Bp + 3 * 32768);        // NN+1
    int* csr     = rp + NN + 1;                   // NE
    int* buck    = csr + NE;                      // BK*BCAP
    int* gcnt    = buck + (size_t)BK * BCAP;      // BK
    int* csrbase = gcnt + BK;                     // BK
    int* gstart  = csrbase + BK;                  // NG+1

    const int gb = (NN * 16 + 255) / 256;         // gather blocks (16 lanes/node)
    const int tb = (NN + 63) / 64;                // transform blocks (64 rows)
    const int cvtb = ((NN * C / 8) + 255) / 256;

    // ---- Bucketed CSR build (shared by all 3 layers) ----
    hipMemsetAsync(gcnt, 0, BK * sizeof(int), stream);
    k_binA<<<ABLK, 256, 0, stream>>>(src, dst, gcnt, buck);
    k_binscan<<<1, 256, 0, stream>>>(gcnt, csrbase, rp);
    k_binB<<<BK, BNW, 0, stream>>>(gcnt, csrbase, buck, rp, csr);

    // ---- Precompute: x->bf16, packed weights, graph bounds ----
    k_cvt_bf16<<<cvtb, 256, 0, stream>>>(x, xb);
    k_pack_w<<<16, 256, 0, stream>>>(W1_rel, W1_root, Bp);
    k_pack_w<<<16, 256, 0, stream>>>(W2_rel, W2_root, Bp + 32768);
    k_pack_w<<<16, 256, 0, stream>>>(W3_rel, W3_root, Bp + 2 * 32768);
    k_gbounds<<<3, 256, 0, stream>>>(batch, gstart);

    // ---- Layer 1 ----
    k_gather<<<gb, 256, 0, stream>>>(xb, rp, csr, aggb);
    k_transform_mfma<true><<<tb, 256, 0, stream>>>(aggb, xb, Bp, b1, hb);

    // ---- Layer 2 (in-place) ----
    k_gather<<<gb, 256, 0, stream>>>(hb, rp, csr, aggb);
    k_transform_mfma<true><<<tb, 256, 0, stream>>>(aggb, hb, Bp + 32768, b2, hb);

    // ---- Layer 3 (no relu, in-place) ----
    k_gather<<<gb, 256, 0, stream>>>(hb, rp, csr, aggb);
    k_transform_mfma<false><<<tb, 256, 0, stream>>>(aggb, hb, Bp + 2 * 32768, b3, hb);

    // ---- Fused pool + final linear ----
    k_pool_final<<<NG, 256, 0, stream>>>(hb, gstart, W_lin, b_lin, out);
}

// Round 11
// 334.952 us; speedup vs baseline: 1.2525x; 1.0246x over previous
//
#include <hip/hip_runtime.h>

static constexpr int NN = 100000;   // nodes
static constexpr int NE = 1600000;  // edges
static constexpr int C  = 128;      // feature dim
static constexpr int OC = 10;       // output classes
static constexpr int NG = 512;      // graphs

// Bucketed CSR build parameters
static constexpr int BSH  = 9;                         // 512 nodes per bucket
static constexpr int BNW  = 1 << BSH;                  // 512
static constexpr int BK   = (NN + BNW - 1) / BNW;      // 196 buckets
static constexpr int BCAP = 12288;                     // slab capacity (avg ~8163)
static constexpr int EPB  = 8192;                      // edges per binA block
static constexpr int ABLK = (NE + EPB - 1) / EPB;      // 196

static constexpr int TSTRIDE = 132;                    // LDS tile row stride (u16)

typedef unsigned short u16;
typedef __attribute__((ext_vector_type(8))) short short8;   // 8 bf16 = 16B
typedef __attribute__((ext_vector_type(8))) short bf16x8;   // MFMA A/B frag
typedef __attribute__((ext_vector_type(4))) float f32x4;    // MFMA C/D frag

__device__ __forceinline__ float bf2f(u16 u) {
    union { float f; unsigned int u32; } v; v.u32 = ((unsigned int)u) << 16; return v.f;
}
__device__ __forceinline__ u16 f2bf(float f) {
    union { float f; unsigned int u; } v; v.f = f;
    unsigned int u = v.u;
    unsigned int r = u + 0x7FFF + ((u >> 16) & 1);   // RNE
    return (u16)(r >> 16);
}

// ---------------------------------------------------------------------------
// Phase A: bin edges into BK buckets by dst>>BSH (L2-local slab writes).
// ---------------------------------------------------------------------------
__global__ __launch_bounds__(256) void k_binA(const int* __restrict__ src,
                                              const int* __restrict__ dst,
                                              int* __restrict__ gcnt,
                                              int* __restrict__ buck) {
    __shared__ int cnt[BK];
    __shared__ int curs[BK];
    int tid = threadIdx.x;
    for (int i = tid; i < BK; i += 256) cnt[i] = 0;
    __syncthreads();
    int e0 = blockIdx.x * EPB;
    for (int i = tid; i < EPB; i += 256) {
        int e = e0 + i;
        if (e < NE) atomicAdd(&cnt[dst[e] >> BSH], 1);
    }
    __syncthreads();
    for (int i = tid; i < BK; i += 256) {
        int c = cnt[i];
        int gb = (c > 0) ? atomicAdd(&gcnt[i], c) : 0;
        curs[i] = i * BCAP + gb;
    }
    __syncthreads();
    for (int i = tid; i < EPB; i += 256) {
        int e = e0 + i;
        if (e < NE) {
            int d = dst[e];
            int b = d >> BSH;
            int p = atomicAdd(&curs[b], 1);
            if (p < (b + 1) * BCAP)
                buck[p] = (src[e] << BSH) | (d & (BNW - 1));
        }
    }
}

// ---------------------------------------------------------------------------
// k_meta: block 0 = exclusive scan of bucket counts (csrbase, rp[NN]=NE);
// blocks 1..3 = graph boundaries via binary search over sorted batch.
// ---------------------------------------------------------------------------
__global__ __launch_bounds__(256) void k_meta(const int* __restrict__ gcnt,
                                              int* __restrict__ csrbase,
                                              int* __restrict__ rp,
                                              const int* __restrict__ batch,
                                              int* __restrict__ gstart) {
    int tid = threadIdx.x;
    if (blockIdx.x == 0) {
        __shared__ int buf[256];
        int v = (tid < BK) ? gcnt[tid] : 0;
        buf[tid] = v;
        __syncthreads();
        for (int off = 1; off < 256; off <<= 1) {
            int t = (tid >= off) ? buf[tid - off] : 0;
            __syncthreads();
            buf[tid] += t;
            __syncthreads();
        }
        if (tid < BK) csrbase[tid] = buf[tid] - v;
        if (tid == 0) rp[NN] = NE;
    } else {
        int g = (blockIdx.x - 1) * 256 + tid;
        if (g > NG) return;
        int lo = 0, hi = NN;
        while (lo < hi) { int mid = (lo + hi) >> 1; if (batch[mid] < g) lo = mid + 1; else hi = mid; }
        gstart[g] = lo;
    }
}

// ---------------------------------------------------------------------------
// Phase B: one block per bucket.  LDS histogram over the bucket's 512 nodes,
// LDS scan -> rp slice, then LDS-cursor scatter into the bucket's contiguous
// CSR window (single block -> L2-local writes).
// ---------------------------------------------------------------------------
__global__ __launch_bounds__(BNW) void k_binB(const int* __restrict__ gcnt,
                                              const int* __restrict__ csrbase,
                                              const int* __restrict__ buck,
                                              int* __restrict__ rp,
                                              int* __restrict__ csr) {
    int b = blockIdx.x;
    int tid = threadIdx.x;
    __shared__ int hist[BNW];     // histogram, then cursor
    __shared__ int scanbuf[BNW];
    int n = gcnt[b];
    if (n > BCAP) n = BCAP;
    int base = csrbase[b];
    const int* bb = buck + (size_t)b * BCAP;

    hist[tid] = 0;
    __syncthreads();
    for (int i = tid; i < n; i += BNW) atomicAdd(&hist[bb[i] & (BNW - 1)], 1);
    __syncthreads();

    int v = hist[tid];
    scanbuf[tid] = v;
    __syncthreads();
    for (int off = 1; off < BNW; off <<= 1) {
        int t = (tid >= off) ? scanbuf[tid - off] : 0;
        __syncthreads();
        scanbuf[tid] += t;
        __syncthreads();
    }
    int excl = scanbuf[tid] - v;
    int node = (b << BSH) + tid;
    if (node < NN) rp[node] = base + excl;
    __syncthreads();
    hist[tid] = base + excl;      // cursor
    __syncthreads();
    for (int i = tid; i < n; i += BNW) {
        int en = bb[i];
        int p = atomicAdd(&hist[en & (BNW - 1)], 1);
        csr[p] = en >> BSH;
    }
}

// ---------------------------------------------------------------------------
// k_prep: blocks 0..47 pack the 3 layers' [W_rel;W_root] into per-lane MFMA
// B-fragment order (bf16); remaining blocks convert x f32 -> bf16.
// ---------------------------------------------------------------------------
__global__ __launch_bounds__(256) void k_prep(
    const float* __restrict__ x, u16* __restrict__ xb,
    const float* __restrict__ W1r, const float* __restrict__ W1o,
    const float* __restrict__ W2r, const float* __restrict__ W2o,
    const float* __restrict__ W3r, const float* __restrict__ W3o,
    u16* __restrict__ Bp) {
    int bid = blockIdx.x;
    if (bid < 48) {
        int layer = bid >> 4;
        const float* Wr = (layer == 0) ? W1r : (layer == 1) ? W2r : W3r;
        const float* Wo = (layer == 0) ? W1o : (layer == 1) ? W2o : W3o;
        u16* out = Bp + layer * 32768;
        int t = (bid & 15) * 256 + threadIdx.x;   // 0..4095
        int lane = t & 63;
        int nfrag = (t >> 6) & 7;
        int kk = t >> 9;
        int col = nfrag * 16 + (lane & 15);
        int k0 = kk * 32 + (lane >> 4) * 8;
        u16 vals[8];
#pragma unroll
        for (int j = 0; j < 8; ++j) {
            int k = k0 + j;
            float w = (k < C) ? Wr[k * C + col] : Wo[(k - C) * C + col];
            vals[j] = f2bf(w);
        }
        *reinterpret_cast<short8*>(out + (size_t)t * 8) = *reinterpret_cast<const short8*>(vals);
    } else {
        int i = (bid - 48) * 256 + threadIdx.x;
        size_t base = (size_t)i * 8;
        if (base >= (size_t)NN * C) return;
        float4 a = *reinterpret_cast<const float4*>(x + base);
        float4 b = *reinterpret_cast<const float4*>(x + base + 4);
        u16 o[8] = { f2bf(a.x), f2bf(a.y), f2bf(a.z), f2bf(a.w),
                     f2bf(b.x), f2bf(b.y), f2bf(b.z), f2bf(b.w) };
        *reinterpret_cast<short8*>(xb + base) = *reinterpret_cast<const short8*>(o);
    }
}

// ---------------------------------------------------------------------------
// Gather-aggregate (bf16): agg[i] = sum_{j in in(i)} h[j].
// WHOLE WAVE PER NODE: lane = (jj 0..3, seg 0..15); 8 edges per iteration
// (2 x 4-edge load instrs in flight), zero intra-wave divergence.
// Epilogue: shfl_xor(32)+shfl_xor(16) sums the 4 jj-groups; lanes 0-15 store.
// ---------------------------------------------------------------------------
__global__ __launch_bounds__(256) void k_gather(const u16* __restrict__ h,
                                                const int* __restrict__ rp,
                                                const int* __restrict__ csr,
                                                u16* __restrict__ agg) {
    int t = blockIdx.x * blockDim.x + threadIdx.x;
    int node = t >> 6;
    if (node >= NN) return;
    int lane = t & 63;
    int jj = lane >> 4;          // edge slot 0..3
    int seg = (lane & 15) * 8;   // element offset within row
    int beg = rp[node], end = rp[node + 1];

    float acc[8] = {};
    int j0 = beg;
    for (; j0 + 8 <= end; j0 += 8) {
        int sa = csr[j0 + jj];
        int sb = csr[j0 + 4 + jj];
        short8 va = *reinterpret_cast<const short8*>(h + (size_t)sa * C + seg);
        short8 vb = *reinterpret_cast<const short8*>(h + (size_t)sb * C + seg);
#pragma unroll
        for (int q = 0; q < 8; ++q) {
            acc[q] += bf2f((u16)va[q]);
            acc[q] += bf2f((u16)vb[q]);
        }
    }
    if (j0 < end) {              // tail: 1..7 edges, predicated per jj-group
        int ja = j0 + jj;
        int jb = j0 + 4 + jj;
        if (ja < end) {
            int sa = csr[ja];
            short8 va = *reinterpret_cast<const short8*>(h + (size_t)sa * C + seg);
#pragma unroll
            for (int q = 0; q < 8; ++q) acc[q] += bf2f((u16)va[q]);
        }
        if (jb < end) {
            int sb = csr[jb];
            short8 vb = *reinterpret_cast<const short8*>(h + (size_t)sb * C + seg);
#pragma unroll
            for (int q = 0; q < 8; ++q) acc[q] += bf2f((u16)vb[q]);
        }
    }

    // reduce across the 4 jj-groups
#pragma unroll
    for (int q = 0; q < 8; ++q) {
        acc[q] += __shfl_xor(acc[q], 32);
        acc[q] += __shfl_xor(acc[q], 16);
    }
    if (lane < 16) {
        u16 o[8];
#pragma unroll
        for (int q = 0; q < 8; ++q) o[q] = f2bf(acc[q]);
        *reinterpret_cast<short8*>(agg + (size_t)node * C + seg) =
            *reinterpret_cast<const short8*>(o);
    }
}

// ---------------------------------------------------------------------------
// MFMA transform: out = [relu]( [agg|h] @ [W_rel;W_root] + b ), bf16 in/out.
// Block = 4 waves x 16 rows = 64 nodes; wave computes 16 x 128.
// Epilogue stages the D-tile in LDS and streams out coalesced 16 B chunks.
// Safe in-place (out == h): each block only reads/writes its own rows.
// ---------------------------------------------------------------------------
template <bool RELU>
__global__ __launch_bounds__(256) void k_transform_mfma(
    const u16* __restrict__ agg, const u16* __restrict__ h,
    const u16* __restrict__ Bp, const float* __restrict__ bias,
    u16* __restrict__ out) {
    __shared__ u16 tile[4][16 * TSTRIDE];   // 16.9 KB
    int wave = threadIdx.x >> 6;
    int lane = threadIdx.x & 63;
    int row0 = blockIdx.x * 64 + wave * 16;
    int arow = row0 + (lane & 15);
    int rclamp = arow < NN ? arow : NN - 1;
    int koff = (lane >> 4) * 8;

    f32x4 acc[8] = {};
#pragma unroll
    for (int kk = 0; kk < 8; ++kk) {
        bf16x8 a;
        if (kk < 4) {
            a = *reinterpret_cast<const bf16x8*>(agg + (size_t)rclamp * C + kk * 32 + koff);
        } else {
            a = *reinterpret_cast<const bf16x8*>(h + (size_t)rclamp * C + (kk - 4) * 32 + koff);
        }
        const u16* bp = Bp + ((size_t)kk * 8 * 64 + lane) * 8;
#pragma unroll
        for (int n = 0; n < 8; ++n) {
            bf16x8 b = *reinterpret_cast<const bf16x8*>(bp + (size_t)n * 64 * 8);
            acc[n] = __builtin_amdgcn_mfma_f32_16x16x32_bf16(a, b, acc[n], 0, 0, 0);
        }
    }

    u16* T = tile[wave];
    int colbase = lane & 15;
    int rloc = (lane >> 4) * 4;
#pragma unroll
    for (int n = 0; n < 8; ++n) {
        int col = n * 16 + colbase;
        float bb = bias[col];
#pragma unroll
        for (int r = 0; r < 4; ++r) {
            float v = acc[n][r] + bb;
            if (RELU) v = fmaxf(v, 0.0f);
            T[(rloc + r) * TSTRIDE + col] = f2bf(v);
        }
    }
    __syncthreads();

#pragma unroll
    for (int k = 0; k < 4; ++k) {
        int idx = k * 64 + lane;
        int lr = idx >> 4;
        int off = (idx & 15) * 8;
        int ro = row0 + lr;
        if (ro < NN) {
            short8 v = *reinterpret_cast<const short8*>(&T[lr * TSTRIDE + off]);
            *reinterpret_cast<short8*>(out + (size_t)ro * C + off) = v;
        }
    }
}

// ---------------------------------------------------------------------------
// Fused mean-pool + final linear.  16 row-slots x 16 col-segments.
// ---------------------------------------------------------------------------
__global__ __launch_bounds__(256) void k_pool_final(
    const u16* __restrict__ h, const int* __restrict__ gstart,
    const float* __restrict__ W_lin, const float* __restrict__ b_lin,
    float* __restrict__ out) {
    int g = blockIdx.x;
    int rowslot = threadIdx.x >> 4;      // 0..15
    int seg = threadIdx.x & 15;          // 0..15 (8 cols each)
    int s = gstart[g], e = gstart[g + 1];

    float acc[8] = {};
    for (int i = s + rowslot; i < e; i += 16) {
        short8 v = *reinterpret_cast<const short8*>(h + (size_t)i * C + seg * 8);
#pragma unroll
        for (int q = 0; q < 8; ++q) acc[q] += bf2f((u16)v[q]);
    }

    __shared__ float red[16][C];         // 8 KB
#pragma unroll
    for (int q = 0; q < 8; ++q) red[rowslot][seg * 8 + q] = acc[q];
    __syncthreads();

    __shared__ float sp[C];
    if (threadIdx.x < C) {
        float sum = 0.0f;
#pragma unroll
        for (int r = 0; r < 16; ++r) sum += red[r][threadIdx.x];
        float cnt = (float)max(e - s, 1);
        sp[threadIdx.x] = sum / cnt;
    }
    __syncthreads();
    if (threadIdx.x < OC) {
        float o = b_lin[threadIdx.x];
#pragma unroll 8
        for (int k = 0; k < C; ++k) o += sp[k] * W_lin[k * OC + threadIdx.x];
        out[g * OC + threadIdx.x] = o;
    }
}

extern "C" void kernel_launch(void* const* d_in, const int* in_sizes, int n_in,
                              void* d_out, int out_size, void* d_ws, size_t ws_size,
                              hipStream_t stream) {
    const float* x       = (const float*)d_in[0];
    const int*   eidx    = (const int*)d_in[1];
    const int*   batch   = (const int*)d_in[2];
    const float* W1_rel  = (const float*)d_in[3];
    const float* b1      = (const float*)d_in[4];
    const float* W1_root = (const float*)d_in[5];
    const float* W2_rel  = (const float*)d_in[6];
    const float* b2      = (const float*)d_in[7];
    const float* W2_root = (const float*)d_in[8];
    const float* W3_rel  = (const float*)d_in[9];
    const float* b3      = (const float*)d_in[10];
    const float* W3_root = (const float*)d_in[11];
    const float* W_lin   = (const float*)d_in[12];
    const float* b_lin   = (const float*)d_in[13];
    float* out = (float*)d_out;

    const int* src = eidx;
    const int* dst = eidx + NE;

    // Workspace layout
    u16* xb   = (u16*)d_ws;                       // NN*C bf16
    u16* hb   = xb + (size_t)NN * C;              // NN*C bf16
    u16* aggb = hb + (size_t)NN * C;              // NN*C bf16
    u16* Bp   = aggb + (size_t)NN * C;            // 3 * 32768 bf16
    int* rp      = (int*)(Bp + 3 * 32768);        // NN+1
    int* csr     = rp + NN + 1;                   // NE
    int* buck    = csr + NE;                      // BK*BCAP
    int* gcnt    = buck + (size_t)BK * BCAP;      // BK
    int* csrbase = gcnt + BK;                     // BK
    int* gstart  = csrbase + BK;                  // NG+1

    const int gb = (NN * 64 + 255) / 256;         // gather blocks (64 lanes/node)
    const int tb = (NN + 63) / 64;                // transform blocks (64 rows)
    const int prepb = 48 + ((NN * C / 8) + 255) / 256;

    // ---- Bucketed CSR build (shared by all 3 layers) ----
    hipMemsetAsync(gcnt, 0, BK * sizeof(int), stream);
    k_binA<<<ABLK, 256, 0, stream>>>(src, dst, gcnt, buck);
    k_meta<<<4, 256, 0, stream>>>(gcnt, csrbase, rp, batch, gstart);
    k_binB<<<BK, BNW, 0, stream>>>(gcnt, csrbase, buck, rp, csr);

    // ---- Precompute: packed weights + x->bf16 (one kernel) ----
    k_prep<<<prepb, 256, 0, stream>>>(x, xb, W1_rel, W1_root, W2_rel, W2_root,
                                      W3_rel, W3_root, Bp);

    // ---- Layer 1 ----
    k_gather<<<gb, 256, 0, stream>>>(xb, rp, csr, aggb);
    k_transform_mfma<true><<<tb, 256, 0, stream>>>(aggb, xb, Bp, b1, hb);

    // ---- Layer 2 (in-place) ----
    k_gather<<<gb, 256, 0, stream>>>(hb, rp, csr, aggb);
    k_transform_mfma<true><<<tb, 256, 0, stream>>>(aggb, hb, Bp + 32768, b2, hb);

    // ---- Layer 3 (no relu, in-place) ----
    k_gather<<<gb, 256, 0, stream>>>(hb, rp, csr, aggb);
    k_transform_mfma<false><<<tb, 256, 0, stream>>>(aggb, hb, Bp + 2 * 32768, b3, hb);

    // ---- Fused pool + final linear ----
    k_pool_final<<<NG, 256, 0, stream>>>(hb, gstart, W_lin, b_lin, out);
}

// Round 12
// 317.256 us; speedup vs baseline: 1.3224x; 1.0558x over previous
//
#include <hip/hip_runtime.h>

static constexpr int NN = 100000;   // nodes
static constexpr int NE = 1600000;  // edges
static constexpr int C  = 128;      // feature dim
static constexpr int OC = 10;       // output classes
static constexpr int NG = 512;      // graphs

// Bucketed CSR build parameters
static constexpr int BSH  = 9;                         // 512 nodes per bucket
static constexpr int BNW  = 1 << BSH;                  // 512
static constexpr int BK   = (NN + BNW - 1) / BNW;      // 196 buckets
static constexpr int BCAP = 12288;                     // slab capacity (avg ~8163)
static constexpr int EPB  = 8192;                      // edges per binA block
static constexpr int ABLK = (NE + EPB - 1) / EPB;      // 196

static constexpr int TSTRIDE = 132;                    // LDS tile row stride (u16)
static constexpr int NSPLIT = 8;                       // blocks per graph in k_gsum

typedef unsigned short u16;
typedef __attribute__((ext_vector_type(8))) short short8;   // 8 bf16 = 16B
typedef __attribute__((ext_vector_type(8))) short bf16x8;   // MFMA A/B frag
typedef __attribute__((ext_vector_type(4))) float f32x4;    // MFMA C/D frag

__device__ __forceinline__ float bf2f(u16 u) {
    union { float f; unsigned int u32; } v; v.u32 = ((unsigned int)u) << 16; return v.f;
}
__device__ __forceinline__ u16 f2bf(float f) {
    union { float f; unsigned int u; } v; v.f = f;
    unsigned int u = v.u;
    unsigned int r = u + 0x7FFF + ((u >> 16) & 1);   // RNE
    return (u16)(r >> 16);
}

// ---------------------------------------------------------------------------
// Phase A: bin edges into BK buckets by dst>>BSH (L2-local slab writes).
// ---------------------------------------------------------------------------
__global__ __launch_bounds__(256) void k_binA(const int* __restrict__ src,
                                              const int* __restrict__ dst,
                                              int* __restrict__ gcnt,
                                              int* __restrict__ buck) {
    __shared__ int cnt[BK];
    __shared__ int curs[BK];
    int tid = threadIdx.x;
    for (int i = tid; i < BK; i += 256) cnt[i] = 0;
    __syncthreads();
    int e0 = blockIdx.x * EPB;
    for (int i = tid; i < EPB; i += 256) {
        int e = e0 + i;
        if (e < NE) atomicAdd(&cnt[dst[e] >> BSH], 1);
    }
    __syncthreads();
    for (int i = tid; i < BK; i += 256) {
        int c = cnt[i];
        int gb = (c > 0) ? atomicAdd(&gcnt[i], c) : 0;
        curs[i] = i * BCAP + gb;
    }
    __syncthreads();
    for (int i = tid; i < EPB; i += 256) {
        int e = e0 + i;
        if (e < NE) {
            int d = dst[e];
            int b = d >> BSH;
            int p = atomicAdd(&curs[b], 1);
            if (p < (b + 1) * BCAP)
                buck[p] = (src[e] << BSH) | (d & (BNW - 1));
        }
    }
}

// ---------------------------------------------------------------------------
// k_meta: block 0 = exclusive scan of bucket counts (csrbase, rp[NN]=NE);
// blocks 1..3 = graph boundaries via binary search over sorted batch.
// ---------------------------------------------------------------------------
__global__ __launch_bounds__(256) void k_meta(const int* __restrict__ gcnt,
                                              int* __restrict__ csrbase,
                                              int* __restrict__ rp,
                                              const int* __restrict__ batch,
                                              int* __restrict__ gstart) {
    int tid = threadIdx.x;
    if (blockIdx.x == 0) {
        __shared__ int buf[256];
        int v = (tid < BK) ? gcnt[tid] : 0;
        buf[tid] = v;
        __syncthreads();
        for (int off = 1; off < 256; off <<= 1) {
            int t = (tid >= off) ? buf[tid - off] : 0;
            __syncthreads();
            buf[tid] += t;
            __syncthreads();
        }
        if (tid < BK) csrbase[tid] = buf[tid] - v;
        if (tid == 0) rp[NN] = NE;
    } else {
        int g = (blockIdx.x - 1) * 256 + tid;
        if (g > NG) return;
        int lo = 0, hi = NN;
        while (lo < hi) { int mid = (lo + hi) >> 1; if (batch[mid] < g) lo = mid + 1; else hi = mid; }
        gstart[g] = lo;
    }
}

// ---------------------------------------------------------------------------
// Phase B: one block per bucket.  LDS histogram over the bucket's 512 nodes,
// LDS scan -> rp slice, then LDS-cursor scatter into the bucket's contiguous
// CSR window (single block -> L2-local writes).
// ---------------------------------------------------------------------------
__global__ __launch_bounds__(BNW) void k_binB(const int* __restrict__ gcnt,
                                              const int* __restrict__ csrbase,
                                              const int* __restrict__ buck,
                                              int* __restrict__ rp,
                                              int* __restrict__ csr) {
    int b = blockIdx.x;
    int tid = threadIdx.x;
    __shared__ int hist[BNW];     // histogram, then cursor
    __shared__ int scanbuf[BNW];
    int n = gcnt[b];
    if (n > BCAP) n = BCAP;
    int base = csrbase[b];
    const int* bb = buck + (size_t)b * BCAP;

    hist[tid] = 0;
    __syncthreads();
    for (int i = tid; i < n; i += BNW) atomicAdd(&hist[bb[i] & (BNW - 1)], 1);
    __syncthreads();

    int v = hist[tid];
    scanbuf[tid] = v;
    __syncthreads();
    for (int off = 1; off < BNW; off <<= 1) {
        int t = (tid >= off) ? scanbuf[tid - off] : 0;
        __syncthreads();
        scanbuf[tid] += t;
        __syncthreads();
    }
    int excl = scanbuf[tid] - v;
    int node = (b << BSH) + tid;
    if (node < NN) rp[node] = base + excl;
    __syncthreads();
    hist[tid] = base + excl;      // cursor
    __syncthreads();
    for (int i = tid; i < n; i += BNW) {
        int en = bb[i];
        int p = atomicAdd(&hist[en & (BNW - 1)], 1);
        csr[p] = en >> BSH;
    }
}

// ---------------------------------------------------------------------------
// k_prep: blocks 0..47 pack layers' [W_rel;W_root] into per-lane MFMA
// B-fragment order (bf16); remaining blocks convert x f32 -> bf16.
// Only layers 1 and 2 need packed weights now (layer 3 is folded).
// ---------------------------------------------------------------------------
__global__ __launch_bounds__(256) void k_prep(
    const float* __restrict__ x, u16* __restrict__ xb,
    const float* __restrict__ W1r, const float* __restrict__ W1o,
    const float* __restrict__ W2r, const float* __restrict__ W2o,
    u16* __restrict__ Bp) {
    int bid = blockIdx.x;
    if (bid < 32) {
        int layer = bid >> 4;
        const float* Wr = (layer == 0) ? W1r : W2r;
        const float* Wo = (layer == 0) ? W1o : W2o;
        u16* out = Bp + layer * 32768;
        int t = (bid & 15) * 256 + threadIdx.x;   // 0..4095
        int lane = t & 63;
        int nfrag = (t >> 6) & 7;
        int kk = t >> 9;
        int col = nfrag * 16 + (lane & 15);
        int k0 = kk * 32 + (lane >> 4) * 8;
        u16 vals[8];
#pragma unroll
        for (int j = 0; j < 8; ++j) {
            int k = k0 + j;
            float w = (k < C) ? Wr[k * C + col] : Wo[(k - C) * C + col];
            vals[j] = f2bf(w);
        }
        *reinterpret_cast<short8*>(out + (size_t)t * 8) = *reinterpret_cast<const short8*>(vals);
    } else {
        int i = (bid - 32) * 256 + threadIdx.x;
        size_t base = (size_t)i * 8;
        if (base >= (size_t)NN * C) return;
        float4 a = *reinterpret_cast<const float4*>(x + base);
        float4 b = *reinterpret_cast<const float4*>(x + base + 4);
        u16 o[8] = { f2bf(a.x), f2bf(a.y), f2bf(a.z), f2bf(a.w),
                     f2bf(b.x), f2bf(b.y), f2bf(b.z), f2bf(b.w) };
        *reinterpret_cast<short8*>(xb + base) = *reinterpret_cast<const short8*>(o);
    }
}

// ---------------------------------------------------------------------------
// k_wfold: fold layer 3 + final linear:  Wrl = W3_rel@W_lin, Wro = W3_root@
// W_lin (128x10 each), bfold = b3@W_lin + b_lin.  Grid = OC blocks x 256.
// ---------------------------------------------------------------------------
__global__ __launch_bounds__(256) void k_wfold(
    const float* __restrict__ W3r, const float* __restrict__ W3o,
    const float* __restrict__ b3, const float* __restrict__ W_lin,
    const float* __restrict__ b_lin,
    float* __restrict__ Wrl, float* __restrict__ Wro, float* __restrict__ bfold) {
    int o = blockIdx.x;
    int tid = threadIdx.x;
    if (tid < 128) {
        float s = 0.0f;
#pragma unroll 8
        for (int c = 0; c < C; ++c) s += W3r[tid * C + c] * W_lin[c * OC + o];
        Wrl[tid * OC + o] = s;
    } else {
        int k = tid - 128;
        float s = 0.0f;
#pragma unroll 8
        for (int c = 0; c < C; ++c) s += W3o[k * C + c] * W_lin[c * OC + o];
        Wro[k * OC + o] = s;
    }
    if (tid == 0) {
        float s = 0.0f;
        for (int c = 0; c < C; ++c) s += b3[c] * W_lin[c * OC + o];
        bfold[o] = b_lin[o] + s;
    }
}

// ---------------------------------------------------------------------------
// Gather-aggregate (bf16): agg[i] = sum_{j in in(i)} h[j].
// Whole wave per node: lane = (jj 0..3, seg 0..15); 8 edges/iteration.
// ---------------------------------------------------------------------------
__global__ __launch_bounds__(256) void k_gather(const u16* __restrict__ h,
                                                const int* __restrict__ rp,
                                                const int* __restrict__ csr,
                                                u16* __restrict__ agg) {
    int t = blockIdx.x * blockDim.x + threadIdx.x;
    int node = t >> 6;
    if (node >= NN) return;
    int lane = t & 63;
    int jj = lane >> 4;          // edge slot 0..3
    int seg = (lane & 15) * 8;   // element offset within row
    int beg = rp[node], end = rp[node + 1];

    float acc[8] = {};
    int j0 = beg;
    for (; j0 + 8 <= end; j0 += 8) {
        int sa = csr[j0 + jj];
        int sb = csr[j0 + 4 + jj];
        short8 va = *reinterpret_cast<const short8*>(h + (size_t)sa * C + seg);
        short8 vb = *reinterpret_cast<const short8*>(h + (size_t)sb * C + seg);
#pragma unroll
        for (int q = 0; q < 8; ++q) {
            acc[q] += bf2f((u16)va[q]);
            acc[q] += bf2f((u16)vb[q]);
        }
    }
    if (j0 < end) {
        int ja = j0 + jj;
        int jb = j0 + 4 + jj;
        if (ja < end) {
            int sa = csr[ja];
            short8 va = *reinterpret_cast<const short8*>(h + (size_t)sa * C + seg);
#pragma unroll
            for (int q = 0; q < 8; ++q) acc[q] += bf2f((u16)va[q]);
        }
        if (jb < end) {
            int sb = csr[jb];
            short8 vb = *reinterpret_cast<const short8*>(h + (size_t)sb * C + seg);
#pragma unroll
            for (int q = 0; q < 8; ++q) acc[q] += bf2f((u16)vb[q]);
        }
    }

#pragma unroll
    for (int q = 0; q < 8; ++q) {
        acc[q] += __shfl_xor(acc[q], 32);
        acc[q] += __shfl_xor(acc[q], 16);
    }
    if (lane < 16) {
        u16 o[8];
#pragma unroll
        for (int q = 0; q < 8; ++q) o[q] = f2bf(acc[q]);
        *reinterpret_cast<short8*>(agg + (size_t)node * C + seg) =
            *reinterpret_cast<const short8*>(o);
    }
}

// ---------------------------------------------------------------------------
// MFMA transform: out = [relu]( [agg|h] @ [W_rel;W_root] + b ), bf16 in/out.
// LDS-staged coalesced epilogue.  Safe in-place.
// ---------------------------------------------------------------------------
template <bool RELU>
__global__ __launch_bounds__(256) void k_transform_mfma(
    const u16* __restrict__ agg, const u16* __restrict__ h,
    const u16* __restrict__ Bp, const float* __restrict__ bias,
    u16* __restrict__ out) {
    __shared__ u16 tile[4][16 * TSTRIDE];   // 16.9 KB
    int wave = threadIdx.x >> 6;
    int lane = threadIdx.x & 63;
    int row0 = blockIdx.x * 64 + wave * 16;
    int arow = row0 + (lane & 15);
    int rclamp = arow < NN ? arow : NN - 1;
    int koff = (lane >> 4) * 8;

    f32x4 acc[8] = {};
#pragma unroll
    for (int kk = 0; kk < 8; ++kk) {
        bf16x8 a;
        if (kk < 4) {
            a = *reinterpret_cast<const bf16x8*>(agg + (size_t)rclamp * C + kk * 32 + koff);
        } else {
            a = *reinterpret_cast<const bf16x8*>(h + (size_t)rclamp * C + (kk - 4) * 32 + koff);
        }
        const u16* bp = Bp + ((size_t)kk * 8 * 64 + lane) * 8;
#pragma unroll
        for (int n = 0; n < 8; ++n) {
            bf16x8 b = *reinterpret_cast<const bf16x8*>(bp + (size_t)n * 64 * 8);
            acc[n] = __builtin_amdgcn_mfma_f32_16x16x32_bf16(a, b, acc[n], 0, 0, 0);
        }
    }

    u16* T = tile[wave];
    int colbase = lane & 15;
    int rloc = (lane >> 4) * 4;
#pragma unroll
    for (int n = 0; n < 8; ++n) {
        int col = n * 16 + colbase;
        float bb = bias[col];
#pragma unroll
        for (int r = 0; r < 4; ++r) {
            float v = acc[n][r] + bb;
            if (RELU) v = fmaxf(v, 0.0f);
            T[(rloc + r) * TSTRIDE + col] = f2bf(v);
        }
    }
    __syncthreads();

#pragma unroll
    for (int k = 0; k < 4; ++k) {
        int idx = k * 64 + lane;
        int lr = idx >> 4;
        int off = (idx & 15) * 8;
        int ro = row0 + lr;
        if (ro < NN) {
            short8 v = *reinterpret_cast<const short8*>(&T[lr * TSTRIDE + off]);
            *reinterpret_cast<short8*>(out + (size_t)ro * C + off) = v;
        }
    }
}

// ---------------------------------------------------------------------------
// k_gsum: layer-3 + pool collapsed.  Per graph g:
//   S_g = sum over its CSR edge window of h2[src],  T_g = sum of its own rows.
// NSPLIT blocks per graph (edge/node sub-ranges) for TLP; atomic-free
// partials -> partial[b*256 + {0..127:S, 128..255:T}].
// ---------------------------------------------------------------------------
__global__ __launch_bounds__(256) void k_gsum(
    const u16* __restrict__ h, const int* __restrict__ rp,
    const int* __restrict__ csr, const int* __restrict__ gstart,
    float* __restrict__ partial) {
    int b = blockIdx.x;
    int g = b >> 3;              // NSPLIT = 8
    int p = b & 7;
    int slot = threadIdx.x >> 4; // 0..15
    int seg = (threadIdx.x & 15) * 8;

    int gs = gstart[g], ge = gstart[g + 1];
    int es = rp[gs], ee = rp[ge];
    int m = ee - es;
    int js = es + (int)(((long long)m * p) >> 3);
    int je = es + (int)(((long long)m * (p + 1)) >> 3);
    int nn = ge - gs;
    int is = gs + (int)(((long long)nn * p) >> 3);
    int ie = gs + (int)(((long long)nn * (p + 1)) >> 3);

    // S: edge-window sum (unroll 2; slot covers residues js+slot+16t)
    float accS[8] = {};
    int j = js + slot;
    for (; j + 16 < je; j += 32) {
        int r0 = csr[j];
        int r1 = csr[j + 16];
        short8 v0 = *reinterpret_cast<const short8*>(h + (size_t)r0 * C + seg);
        short8 v1 = *reinterpret_cast<const short8*>(h + (size_t)r1 * C + seg);
#pragma unroll
        for (int q = 0; q < 8; ++q) {
            accS[q] += bf2f((u16)v0[q]);
            accS[q] += bf2f((u16)v1[q]);
        }
    }
    if (j < je) {
        int r0 = csr[j];
        short8 v0 = *reinterpret_cast<const short8*>(h + (size_t)r0 * C + seg);
#pragma unroll
        for (int q = 0; q < 8; ++q) accS[q] += bf2f((u16)v0[q]);
    }

    // T: own-rows sum (coalesced)
    float accT[8] = {};
    for (int i = is + slot; i < ie; i += 16) {
        short8 v = *reinterpret_cast<const short8*>(h + (size_t)i * C + seg);
#pragma unroll
        for (int q = 0; q < 8; ++q) accT[q] += bf2f((u16)v[q]);
    }

    __shared__ float red[16][C];   // 8 KB, used twice
#pragma unroll
    for (int q = 0; q < 8; ++q) red[slot][seg + q] = accS[q];
    __syncthreads();
    if (threadIdx.x < C) {
        float s = 0.0f;
#pragma unroll
        for (int r = 0; r < 16; ++r) s += red[r][threadIdx.x];
        partial[(size_t)b * 256 + threadIdx.x] = s;
    }
    __syncthreads();
#pragma unroll
    for (int q = 0; q < 8; ++q) red[slot][seg + q] = accT[q];
    __syncthreads();
    if (threadIdx.x < C) {
        float s = 0.0f;
#pragma unroll
        for (int r = 0; r < 16; ++r) s += red[r][threadIdx.x];
        partial[(size_t)b * 256 + 128 + threadIdx.x] = s;
    }
}

// ---------------------------------------------------------------------------
// k_gout: reduce NSPLIT partials, then out_g = (S@Wrl + T@Wro)/n + bfold.
// Grid = NG blocks x 128 threads.
// ---------------------------------------------------------------------------
__global__ __launch_bounds__(128) void k_gout(
    const float* __restrict__ partial, const int* __restrict__ gstart,
    const float* __restrict__ Wrl, const float* __restrict__ Wro,
    const float* __restrict__ bfold, float* __restrict__ out) {
    int g = blockIdx.x;
    int k = threadIdx.x;
    __shared__ float S[C], T[C];
    float s = 0.0f, t = 0.0f;
#pragma unroll
    for (int p = 0; p < NSPLIT; ++p) {
        s += partial[((size_t)(g * NSPLIT + p)) * 256 + k];
        t += partial[((size_t)(g * NSPLIT + p)) * 256 + 128 + k];
    }
    S[k] = s;
    T[k] = t;
    __syncthreads();
    if (k < OC) {
        int n = gstart[g + 1] - gstart[g];
        float inv = 1.0f / (float)max(n, 1);
        float o = bfold[k];
#pragma unroll 8
        for (int kk = 0; kk < C; ++kk)
            o += (S[kk] * Wrl[kk * OC + k] + T[kk] * Wro[kk * OC + k]) * inv;
        out[g * OC + k] = o;
    }
}

extern "C" void kernel_launch(void* const* d_in, const int* in_sizes, int n_in,
                              void* d_out, int out_size, void* d_ws, size_t ws_size,
                              hipStream_t stream) {
    const float* x       = (const float*)d_in[0];
    const int*   eidx    = (const int*)d_in[1];
    const int*   batch   = (const int*)d_in[2];
    const float* W1_rel  = (const float*)d_in[3];
    const float* b1      = (const float*)d_in[4];
    const float* W1_root = (const float*)d_in[5];
    const float* W2_rel  = (const float*)d_in[6];
    const float* b2      = (const float*)d_in[7];
    const float* W2_root = (const float*)d_in[8];
    const float* W3_rel  = (const float*)d_in[9];
    const float* b3      = (const float*)d_in[10];
    const float* W3_root = (const float*)d_in[11];
    const float* W_lin   = (const float*)d_in[12];
    const float* b_lin   = (const float*)d_in[13];
    float* out = (float*)d_out;

    const int* src = eidx;
    const int* dst = eidx + NE;

    // Workspace layout
    u16* xb   = (u16*)d_ws;                       // NN*C bf16
    u16* hb   = xb + (size_t)NN * C;              // NN*C bf16
    u16* aggb = hb + (size_t)NN * C;              // NN*C bf16
    u16* Bp   = aggb + (size_t)NN * C;            // 2 * 32768 bf16
    int* rp      = (int*)(Bp + 2 * 32768);        // NN+1
    int* csr     = rp + NN + 1;                   // NE
    int* buck    = csr + NE;                      // BK*BCAP
    int* gcnt    = buck + (size_t)BK * BCAP;      // BK
    int* csrbase = gcnt + BK;                     // BK
    int* gstart  = csrbase + BK;                  // NG+1
    float* partial = (float*)(gstart + NG + 2);   // NG*NSPLIT*256
    float* Wrl   = partial + (size_t)NG * NSPLIT * 256;  // 128*OC
    float* Wro   = Wrl + C * OC;                  // 128*OC
    float* bfold = Wro + C * OC;                  // OC

    const int gb = (NN * 64 + 255) / 256;         // gather blocks (64 lanes/node)
    const int tb = (NN + 63) / 64;                // transform blocks (64 rows)
    const int prepb = 32 + ((NN * C / 8) + 255) / 256;

    // ---- Bucketed CSR build (shared by all layers) ----
    hipMemsetAsync(gcnt, 0, BK * sizeof(int), stream);
    k_binA<<<ABLK, 256, 0, stream>>>(src, dst, gcnt, buck);
    k_meta<<<4, 256, 0, stream>>>(gcnt, csrbase, rp, batch, gstart);
    k_binB<<<BK, BNW, 0, stream>>>(gcnt, csrbase, buck, rp, csr);

    // ---- Precompute: packed weights (L1,L2) + x->bf16 + folded L3 weights ----
    k_prep<<<prepb, 256, 0, stream>>>(x, xb, W1_rel, W1_root, W2_rel, W2_root, Bp);
    k_wfold<<<OC, 256, 0, stream>>>(W3_rel, W3_root, b3, W_lin, b_lin, Wrl, Wro, bfold);

    // ---- Layer 1 ----
    k_gather<<<gb, 256, 0, stream>>>(xb, rp, csr, aggb);
    k_transform_mfma<true><<<tb, 256, 0, stream>>>(aggb, xb, Bp, b1, hb);

    // ---- Layer 2 (in-place) ----
    k_gather<<<gb, 256, 0, stream>>>(hb, rp, csr, aggb);
    k_transform_mfma<true><<<tb, 256, 0, stream>>>(aggb, hb, Bp + 32768, b2, hb);

    // ---- Layer 3 + mean-pool + final linear, algebraically collapsed ----
    k_gsum<<<NG * NSPLIT, 256, 0, stream>>>(hb, rp, csr, gstart, partial);
    k_gout<<<NG, 128, 0, stream>>>(partial, gstart, Wrl, Wro, bfold, out);
}

// Round 13
// 309.002 us; speedup vs baseline: 1.3577x; 1.0267x over previous
//
#include <hip/hip_runtime.h>

static constexpr int NN = 100000;   // nodes
static constexpr int NE = 1600000;  // edges
static constexpr int C  = 128;      // feature dim
static constexpr int OC = 10;       // output classes
static constexpr int NG = 512;      // graphs

// Bucketed CSR build parameters
static constexpr int BSH  = 9;                         // 512 nodes per bucket
static constexpr int BNW  = 1 << BSH;                  // 512
static constexpr int BK   = (NN + BNW - 1) / BNW;      // 196 buckets
static constexpr int BCAP = 12288;                     // slab capacity (avg ~8163)
static constexpr int EPB  = 4096;                      // edges per binA block
static constexpr int ABLK = (NE + EPB - 1) / EPB;      // 391

static constexpr int TSTRIDE = 132;                    // LDS tile row stride (u16)
static constexpr int NSPLIT = 8;                       // blocks per graph in k_gsum

typedef unsigned short u16;
typedef __attribute__((ext_vector_type(8))) short short8;   // 8 bf16 = 16B
typedef __attribute__((ext_vector_type(8))) short bf16x8;   // MFMA A/B frag
typedef __attribute__((ext_vector_type(4))) float f32x4;    // MFMA C/D frag

__device__ __forceinline__ float bf2f(u16 u) {
    union { float f; unsigned int u32; } v; v.u32 = ((unsigned int)u) << 16; return v.f;
}
__device__ __forceinline__ u16 f2bf(float f) {
    union { float f; unsigned int u; } v; v.f = f;
    unsigned int u = v.u;
    unsigned int r = u + 0x7FFF + ((u >> 16) & 1);   // RNE
    return (u16)(r >> 16);
}

// ---------------------------------------------------------------------------
// Phase A: bin edges into BK buckets by dst>>BSH (L2-local slab writes).
// ---------------------------------------------------------------------------
__global__ __launch_bounds__(256) void k_binA(const int* __restrict__ src,
                                              const int* __restrict__ dst,
                                              int* __restrict__ gcnt,
                                              int* __restrict__ buck) {
    __shared__ int cnt[BK];
    __shared__ int curs[BK];
    int tid = threadIdx.x;
    for (int i = tid; i < BK; i += 256) cnt[i] = 0;
    __syncthreads();
    int e0 = blockIdx.x * EPB;
    for (int i = tid; i < EPB; i += 256) {
        int e = e0 + i;
        if (e < NE) atomicAdd(&cnt[dst[e] >> BSH], 1);
    }
    __syncthreads();
    for (int i = tid; i < BK; i += 256) {
        int c = cnt[i];
        int gb = (c > 0) ? atomicAdd(&gcnt[i], c) : 0;
        curs[i] = i * BCAP + gb;
    }
    __syncthreads();
    for (int i = tid; i < EPB; i += 256) {
        int e = e0 + i;
        if (e < NE) {
            int d = dst[e];
            int b = d >> BSH;
            int p = atomicAdd(&curs[b], 1);
            if (p < (b + 1) * BCAP)
                buck[p] = (src[e] << BSH) | (d & (BNW - 1));
        }
    }
}

// ---------------------------------------------------------------------------
// Phase B: one block per bucket.  Self-computes its CSR base (scan of gcnt),
// LDS histogram over the bucket's 512 nodes, LDS scan -> rp slice, then
// LDS-cursor scatter into the bucket's contiguous CSR window.
// ---------------------------------------------------------------------------
__global__ __launch_bounds__(BNW) void k_binB(const int* __restrict__ gcnt,
                                              const int* __restrict__ buck,
                                              int* __restrict__ rp,
                                              int* __restrict__ csr) {
    int b = blockIdx.x;
    int tid = threadIdx.x;
    __shared__ int hist[BNW];     // histogram, then cursor
    __shared__ int scanbuf[BNW];

    // base = sum of gcnt[0..b) via block scan (b < BK <= 196 < 512)
    scanbuf[tid] = (tid < b) ? gcnt[tid] : 0;
    __syncthreads();
    for (int off = 1; off < BNW; off <<= 1) {
        int t = (tid >= off) ? scanbuf[tid - off] : 0;
        __syncthreads();
        scanbuf[tid] += t;
        __syncthreads();
    }
    int base = scanbuf[BNW - 1];

    int n = gcnt[b];
    if (n > BCAP) n = BCAP;
    const int* bb = buck + (size_t)b * BCAP;

    hist[tid] = 0;
    __syncthreads();
    for (int i = tid; i < n; i += BNW) atomicAdd(&hist[bb[i] & (BNW - 1)], 1);
    __syncthreads();

    int v = hist[tid];
    scanbuf[tid] = v;
    __syncthreads();
    for (int off = 1; off < BNW; off <<= 1) {
        int t = (tid >= off) ? scanbuf[tid - off] : 0;
        __syncthreads();
        scanbuf[tid] += t;
        __syncthreads();
    }
    int excl = scanbuf[tid] - v;
    int node = (b << BSH) + tid;
    if (node < NN) rp[node] = base + excl;
    if (b == 0 && tid == 0) rp[NN] = NE;
    __syncthreads();
    hist[tid] = base + excl;      // cursor
    __syncthreads();
    for (int i = tid; i < n; i += BNW) {
        int en = bb[i];
        int p = atomicAdd(&hist[en & (BNW - 1)], 1);
        csr[p] = en >> BSH;
    }
}

// ---------------------------------------------------------------------------
// k_prep: blocks 0..31 pack L1/L2 [W_rel;W_root] into MFMA B-frag order;
// blocks 32..34 compute graph boundaries (binary search over sorted batch);
// blocks 35..44 fold layer 3 + final linear (Wrl/Wro/bfold);
// remaining blocks convert x f32 -> bf16.
// ---------------------------------------------------------------------------
__global__ __launch_bounds__(256) void k_prep(
    const float* __restrict__ x, u16* __restrict__ xb,
    const float* __restrict__ W1r, const float* __restrict__ W1o,
    const float* __restrict__ W2r, const float* __restrict__ W2o,
    u16* __restrict__ Bp,
    const int* __restrict__ batch, int* __restrict__ gstart,
    const float* __restrict__ W3r, const float* __restrict__ W3o,
    const float* __restrict__ b3, const float* __restrict__ W_lin,
    const float* __restrict__ b_lin,
    float* __restrict__ Wrl, float* __restrict__ Wro, float* __restrict__ bfold) {
    int bid = blockIdx.x;
    int tid = threadIdx.x;
    if (bid < 32) {
        int layer = bid >> 4;
        const float* Wr = (layer == 0) ? W1r : W2r;
        const float* Wo = (layer == 0) ? W1o : W2o;
        u16* outp = Bp + layer * 32768;
        int t = (bid & 15) * 256 + tid;           // 0..4095
        int lane = t & 63;
        int nfrag = (t >> 6) & 7;
        int kk = t >> 9;
        int col = nfrag * 16 + (lane & 15);
        int k0 = kk * 32 + (lane >> 4) * 8;
        u16 vals[8];
#pragma unroll
        for (int j = 0; j < 8; ++j) {
            int k = k0 + j;
            float w = (k < C) ? Wr[k * C + col] : Wo[(k - C) * C + col];
            vals[j] = f2bf(w);
        }
        *reinterpret_cast<short8*>(outp + (size_t)t * 8) = *reinterpret_cast<const short8*>(vals);
    } else if (bid < 35) {
        int g = (bid - 32) * 256 + tid;
        if (g > NG) return;
        int lo = 0, hi = NN;
        while (lo < hi) { int mid = (lo + hi) >> 1; if (batch[mid] < g) lo = mid + 1; else hi = mid; }
        gstart[g] = lo;
    } else if (bid < 45) {
        int o = bid - 35;
        if (tid < 128) {
            float s = 0.0f;
#pragma unroll 8
            for (int c = 0; c < C; ++c) s += W3r[tid * C + c] * W_lin[c * OC + o];
            Wrl[tid * OC + o] = s;
        } else {
            int k = tid - 128;
            float s = 0.0f;
#pragma unroll 8
            for (int c = 0; c < C; ++c) s += W3o[k * C + c] * W_lin[c * OC + o];
            Wro[k * OC + o] = s;
        }
        if (tid == 0) {
            float s = 0.0f;
            for (int c = 0; c < C; ++c) s += b3[c] * W_lin[c * OC + o];
            bfold[o] = b_lin[o] + s;
        }
    } else {
        int i = (bid - 45) * 256 + tid;
        size_t base = (size_t)i * 8;
        if (base >= (size_t)NN * C) return;
        float4 a = *reinterpret_cast<const float4*>(x + base);
        float4 b = *reinterpret_cast<const float4*>(x + base + 4);
        u16 o[8] = { f2bf(a.x), f2bf(a.y), f2bf(a.z), f2bf(a.w),
                     f2bf(b.x), f2bf(b.y), f2bf(b.z), f2bf(b.w) };
        *reinterpret_cast<short8*>(xb + base) = *reinterpret_cast<const short8*>(o);
    }
}

// ---------------------------------------------------------------------------
// Gather-aggregate (bf16): agg[i] = sum_{j in in(i)} h[j].
// Whole wave per node: lane = (jj 0..3, seg 0..15); 8 edges/iteration.
// ---------------------------------------------------------------------------
__global__ __launch_bounds__(256) void k_gather(const u16* __restrict__ h,
                                                const int* __restrict__ rp,
                                                const int* __restrict__ csr,
                                                u16* __restrict__ agg) {
    int t = blockIdx.x * blockDim.x + threadIdx.x;
    int node = t >> 6;
    if (node >= NN) return;
    int lane = t & 63;
    int jj = lane >> 4;          // edge slot 0..3
    int seg = (lane & 15) * 8;   // element offset within row
    int beg = rp[node], end = rp[node + 1];

    float acc[8] = {};
    int j0 = beg;
    for (; j0 + 8 <= end; j0 += 8) {
        int sa = csr[j0 + jj];
        int sb = csr[j0 + 4 + jj];
        short8 va = *reinterpret_cast<const short8*>(h + (size_t)sa * C + seg);
        short8 vb = *reinterpret_cast<const short8*>(h + (size_t)sb * C + seg);
#pragma unroll
        for (int q = 0; q < 8; ++q) {
            acc[q] += bf2f((u16)va[q]);
            acc[q] += bf2f((u16)vb[q]);
        }
    }
    if (j0 < end) {
        int ja = j0 + jj;
        int jb = j0 + 4 + jj;
        if (ja < end) {
            int sa = csr[ja];
            short8 va = *reinterpret_cast<const short8*>(h + (size_t)sa * C + seg);
#pragma unroll
            for (int q = 0; q < 8; ++q) acc[q] += bf2f((u16)va[q]);
        }
        if (jb < end) {
            int sb = csr[jb];
            short8 vb = *reinterpret_cast<const short8*>(h + (size_t)sb * C + seg);
#pragma unroll
            for (int q = 0; q < 8; ++q) acc[q] += bf2f((u16)vb[q]);
        }
    }

#pragma unroll
    for (int q = 0; q < 8; ++q) {
        acc[q] += __shfl_xor(acc[q], 32);
        acc[q] += __shfl_xor(acc[q], 16);
    }
    if (lane < 16) {
        u16 o[8];
#pragma unroll
        for (int q = 0; q < 8; ++q) o[q] = f2bf(acc[q]);
        *reinterpret_cast<short8*>(agg + (size_t)node * C + seg) =
            *reinterpret_cast<const short8*>(o);
    }
}

// ---------------------------------------------------------------------------
// MFMA transform: out = [relu]( [agg|h] @ [W_rel;W_root] + b ), bf16 in/out.
// LDS-staged coalesced epilogue.  Safe in-place.
// TSUM: additionally accumulate per-graph column sums of the output tile
// (run-length over batch[], ~1.3 f32 atomicAdd flushes per block per column).
// ---------------------------------------------------------------------------
template <bool RELU, bool TSUM>
__global__ __launch_bounds__(256) void k_transform_mfma(
    const u16* __restrict__ agg, const u16* __restrict__ h,
    const u16* __restrict__ Bp, const float* __restrict__ bias,
    u16* __restrict__ out,
    const int* __restrict__ batch, float* __restrict__ Tpart) {
    __shared__ u16 tile[4][16 * TSTRIDE];   // 16.9 KB
    int wave = threadIdx.x >> 6;
    int lane = threadIdx.x & 63;
    int row0 = blockIdx.x * 64 + wave * 16;
    int arow = row0 + (lane & 15);
    int rclamp = arow < NN ? arow : NN - 1;
    int koff = (lane >> 4) * 8;

    f32x4 acc[8] = {};
#pragma unroll
    for (int kk = 0; kk < 8; ++kk) {
        bf16x8 a;
        if (kk < 4) {
            a = *reinterpret_cast<const bf16x8*>(agg + (size_t)rclamp * C + kk * 32 + koff);
        } else {
            a = *reinterpret_cast<const bf16x8*>(h + (size_t)rclamp * C + (kk - 4) * 32 + koff);
        }
        const u16* bp = Bp + ((size_t)kk * 8 * 64 + lane) * 8;
#pragma unroll
        for (int n = 0; n < 8; ++n) {
            bf16x8 b = *reinterpret_cast<const bf16x8*>(bp + (size_t)n * 64 * 8);
            acc[n] = __builtin_amdgcn_mfma_f32_16x16x32_bf16(a, b, acc[n], 0, 0, 0);
        }
    }

    u16* T = tile[wave];
    int colbase = lane & 15;
    int rloc = (lane >> 4) * 4;
#pragma unroll
    for (int n = 0; n < 8; ++n) {
        int col = n * 16 + colbase;
        float bb = bias[col];
#pragma unroll
        for (int r = 0; r < 4; ++r) {
            float v = acc[n][r] + bb;
            if (RELU) v = fmaxf(v, 0.0f);
            T[(rloc + r) * TSTRIDE + col] = f2bf(v);
        }
    }
    __syncthreads();

#pragma unroll
    for (int k = 0; k < 4; ++k) {
        int idx = k * 64 + lane;
        int lr = idx >> 4;
        int off = (idx & 15) * 8;
        int ro = row0 + lr;
        if (ro < NN) {
            short8 v = *reinterpret_cast<const short8*>(&T[lr * TSTRIDE + off]);
            *reinterpret_cast<short8*>(out + (size_t)ro * C + off) = v;
        }
    }

    if (TSUM) {
        if (threadIdx.x < C) {
            int c = threadIdx.x;
            int base = blockIdx.x * 64;
            float run = 0.0f;
            int curg = -1;
            for (int r = 0; r < 64; ++r) {
                int ro = base + r;
                if (ro >= NN) break;
                int g = batch[ro];
                if (g != curg) {
                    if (curg >= 0) atomicAdd(&Tpart[(size_t)curg * C + c], run);
                    run = 0.0f;
                    curg = g;
                }
                run += bf2f(tile[r >> 4][(r & 15) * TSTRIDE + c]);
            }
            if (curg >= 0) atomicAdd(&Tpart[(size_t)curg * C + c], run);
        }
    }
}

// ---------------------------------------------------------------------------
// k_gsum: layer-3 edge sum only.  Per graph g (NSPLIT blocks each):
// S_g = sum over its contiguous CSR edge window of h2[src].  ILP-4 loop.
// ---------------------------------------------------------------------------
__global__ __launch_bounds__(256) void k_gsum(
    const u16* __restrict__ h, const int* __restrict__ rp,
    const int* __restrict__ csr, const int* __restrict__ gstart,
    float* __restrict__ partial) {
    int b = blockIdx.x;
    int g = b >> 3;              // NSPLIT = 8
    int p = b & 7;
    int slot = threadIdx.x >> 4; // 0..15
    int seg = (threadIdx.x & 15) * 8;

    int gs = gstart[g], ge = gstart[g + 1];
    int es = rp[gs], ee = rp[ge];
    int m = ee - es;
    int js = es + (int)(((long long)m * p) >> 3);
    int je = es + (int)(((long long)m * (p + 1)) >> 3);

    float acc[8] = {};
    int j = js + slot;
    for (; j + 48 < je; j += 64) {
        int r0 = csr[j];
        int r1 = csr[j + 16];
        int r2 = csr[j + 32];
        int r3 = csr[j + 48];
        short8 v0 = *reinterpret_cast<const short8*>(h + (size_t)r0 * C + seg);
        short8 v1 = *reinterpret_cast<const short8*>(h + (size_t)r1 * C + seg);
        short8 v2 = *reinterpret_cast<const short8*>(h + (size_t)r2 * C + seg);
        short8 v3 = *reinterpret_cast<const short8*>(h + (size_t)r3 * C + seg);
#pragma unroll
        for (int q = 0; q < 8; ++q) {
            acc[q] += bf2f((u16)v0[q]);
            acc[q] += bf2f((u16)v1[q]);
            acc[q] += bf2f((u16)v2[q]);
            acc[q] += bf2f((u16)v3[q]);
        }
    }
    for (; j < je; j += 16) {
        int r0 = csr[j];
        short8 v0 = *reinterpret_cast<const short8*>(h + (size_t)r0 * C + seg);
#pragma unroll
        for (int q = 0; q < 8; ++q) acc[q] += bf2f((u16)v0[q]);
    }

    __shared__ float red[16][C];   // 8 KB
#pragma unroll
    for (int q = 0; q < 8; ++q) red[slot][seg + q] = acc[q];
    __syncthreads();
    if (threadIdx.x < C) {
        float s = 0.0f;
#pragma unroll
        for (int r = 0; r < 16; ++r) s += red[r][threadIdx.x];
        partial[(size_t)b * C + threadIdx.x] = s;
    }
}

// ---------------------------------------------------------------------------
// k_gout: reduce NSPLIT S-partials + read Tpart, then
// out_g = (S@Wrl + T@Wro)/n + bfold.  Grid = NG blocks x 128 threads.
// ---------------------------------------------------------------------------
__global__ __launch_bounds__(128) void k_gout(
    const float* __restrict__ partial, const float* __restrict__ Tpart,
    const int* __restrict__ gstart,
    const float* __restrict__ Wrl, const float* __restrict__ Wro,
    const float* __restrict__ bfold, float* __restrict__ out) {
    int g = blockIdx.x;
    int k = threadIdx.x;
    __shared__ float S[C], T[C];
    float s = 0.0f;
#pragma unroll
    for (int p = 0; p < NSPLIT; ++p)
        s += partial[((size_t)(g * NSPLIT + p)) * C + k];
    S[k] = s;
    T[k] = Tpart[(size_t)g * C + k];
    __syncthreads();
    if (k < OC) {
        int n = gstart[g + 1] - gstart[g];
        float inv = 1.0f / (float)max(n, 1);
        float o = bfold[k];
#pragma unroll 8
        for (int kk = 0; kk < C; ++kk)
            o += (S[kk] * Wrl[kk * OC + k] + T[kk] * Wro[kk * OC + k]) * inv;
        out[g * OC + k] = o;
    }
}

extern "C" void kernel_launch(void* const* d_in, const int* in_sizes, int n_in,
                              void* d_out, int out_size, void* d_ws, size_t ws_size,
                              hipStream_t stream) {
    const float* x       = (const float*)d_in[0];
    const int*   eidx    = (const int*)d_in[1];
    const int*   batch   = (const int*)d_in[2];
    const float* W1_rel  = (const float*)d_in[3];
    const float* b1      = (const float*)d_in[4];
    const float* W1_root = (const float*)d_in[5];
    const float* W2_rel  = (const float*)d_in[6];
    const float* b2      = (const float*)d_in[7];
    const float* W2_root = (const float*)d_in[8];
    const float* W3_rel  = (const float*)d_in[9];
    const float* b3      = (const float*)d_in[10];
    const float* W3_root = (const float*)d_in[11];
    const float* W_lin   = (const float*)d_in[12];
    const float* b_lin   = (const float*)d_in[13];
    float* out = (float*)d_out;

    const int* src = eidx;
    const int* dst = eidx + NE;

    // Workspace layout
    u16* xb   = (u16*)d_ws;                       // NN*C bf16
    u16* hb   = xb + (size_t)NN * C;              // NN*C bf16
    u16* aggb = hb + (size_t)NN * C;              // NN*C bf16
    u16* Bp   = aggb + (size_t)NN * C;            // 2 * 32768 bf16
    int* rp      = (int*)(Bp + 2 * 32768);        // NN+1
    int* csr     = rp + NN + 1;                   // NE
    int* buck    = csr + NE;                      // BK*BCAP
    int* gcnt    = buck + (size_t)BK * BCAP;      // BK        (zeroed together
    float* Tpart = (float*)(gcnt + BK);           // NG*C       with Tpart)
    int* gstart  = (int*)(Tpart + (size_t)NG * C);// NG+1
    float* partial = (float*)(gstart + NG + 2);   // NG*NSPLIT*C
    float* Wrl   = partial + (size_t)NG * NSPLIT * C;    // C*OC
    float* Wro   = Wrl + C * OC;                  // C*OC
    float* bfold = Wro + C * OC;                  // OC

    const int gb = (NN * 64 + 255) / 256;         // gather blocks (64 lanes/node)
    const int tb = (NN + 63) / 64;                // transform blocks (64 rows)
    const int prepb = 45 + ((NN * C / 8) + 255) / 256;

    // ---- Bucketed CSR build (shared by all layers) ----
    hipMemsetAsync(gcnt, 0, BK * sizeof(int) + (size_t)NG * C * sizeof(float), stream);
    k_binA<<<ABLK, 256, 0, stream>>>(src, dst, gcnt, buck);
    k_binB<<<BK, BNW, 0, stream>>>(gcnt, buck, rp, csr);

    // ---- Precompute: packed weights + gbounds + folded L3 + x->bf16 ----
    k_prep<<<prepb, 256, 0, stream>>>(x, xb, W1_rel, W1_root, W2_rel, W2_root, Bp,
                                      batch, gstart, W3_rel, W3_root, b3, W_lin,
                                      b_lin, Wrl, Wro, bfold);

    // ---- Layer 1 ----
    k_gather<<<gb, 256, 0, stream>>>(xb, rp, csr, aggb);
    k_transform_mfma<true, false><<<tb, 256, 0, stream>>>(aggb, xb, Bp, b1, hb,
                                                          batch, Tpart);

    // ---- Layer 2 (in-place; epilogue accumulates per-graph T sums) ----
    k_gather<<<gb, 256, 0, stream>>>(hb, rp, csr, aggb);
    k_transform_mfma<true, true><<<tb, 256, 0, stream>>>(aggb, hb, Bp + 32768, b2,
                                                         hb, batch, Tpart);

    // ---- Layer 3 + mean-pool + final linear, algebraically collapsed ----
    k_gsum<<<NG * NSPLIT, 256, 0, stream>>>(hb, rp, csr, gstart, partial);
    k_gout<<<NG, 128, 0, stream>>>(partial, Tpart, gstart, Wrl, Wro, bfold, out);
}

// Round 14
// 294.755 us; speedup vs baseline: 1.4233x; 1.0483x over previous
//
#include <hip/hip_runtime.h>

static constexpr int NN = 100000;   // nodes
static constexpr int NE = 1600000;  // edges
static constexpr int C  = 128;      // feature dim
static constexpr int OC = 10;       // output classes
static constexpr int NG = 512;      // graphs

// Bucketed CSR build parameters
static constexpr int BSH  = 9;                         // 512 nodes per bucket
static constexpr int BNW  = 1 << BSH;                  // 512
static constexpr int BK   = (NN + BNW - 1) / BNW;      // 196 buckets
static constexpr int BCAP = 12288;                     // slab capacity (avg ~8163)
static constexpr int EPB  = 4096;                      // edges per binA block
static constexpr int ABLK = (NE + EPB - 1) / EPB;      // 391

static constexpr int TSTRIDE = 132;                    // LDS tile row stride (u16)
static constexpr int NSPLIT = 8;                       // blocks per graph in k_gsum

// merged binB+prep block-range bases (512-thread blocks)
static constexpr int PB_PACK = BK;                     // 16 blocks: weight pack
static constexpr int PB_GB   = PB_PACK + 16;           // 2 blocks: gbounds
static constexpr int PB_WF   = PB_GB + 2;              // 5 blocks: wfold
static constexpr int PB_CVT  = PB_WF + 5;              // 3125 blocks: x->bf16
static constexpr int PB_TOT  = PB_CVT + (NN * C / 8 + 511) / 512;

typedef unsigned short u16;
typedef __attribute__((ext_vector_type(8))) short short8;   // 8 bf16 = 16B
typedef __attribute__((ext_vector_type(8))) short bf16x8;   // MFMA A/B frag
typedef __attribute__((ext_vector_type(4))) float f32x4;    // MFMA C/D frag

__device__ __forceinline__ float bf2f(u16 u) {
    union { float f; unsigned int u32; } v; v.u32 = ((unsigned int)u) << 16; return v.f;
}
__device__ __forceinline__ u16 f2bf(float f) {
    union { float f; unsigned int u; } v; v.f = f;
    unsigned int u = v.u;
    unsigned int r = u + 0x7FFF + ((u >> 16) & 1);   // RNE
    return (u16)(r >> 16);
}

// ---------------------------------------------------------------------------
// Phase A: bin edges into BK buckets by dst>>BSH (L2-local slab writes).
// ---------------------------------------------------------------------------
__global__ __launch_bounds__(256) void k_binA(const int* __restrict__ src,
                                              const int* __restrict__ dst,
                                              int* __restrict__ gcnt,
                                              int* __restrict__ buck) {
    __shared__ int cnt[BK];
    __shared__ int curs[BK];
    int tid = threadIdx.x;
    for (int i = tid; i < BK; i += 256) cnt[i] = 0;
    __syncthreads();
    int e0 = blockIdx.x * EPB;
    for (int i = tid; i < EPB; i += 256) {
        int e = e0 + i;
        if (e < NE) atomicAdd(&cnt[dst[e] >> BSH], 1);
    }
    __syncthreads();
    for (int i = tid; i < BK; i += 256) {
        int c = cnt[i];
        int gb = (c > 0) ? atomicAdd(&gcnt[i], c) : 0;
        curs[i] = i * BCAP + gb;
    }
    __syncthreads();
    for (int i = tid; i < EPB; i += 256) {
        int e = e0 + i;
        if (e < NE) {
            int d = dst[e];
            int b = d >> BSH;
            int p = atomicAdd(&curs[b], 1);
            if (p < (b + 1) * BCAP)
                buck[p] = (src[e] << BSH) | (d & (BNW - 1));
        }
    }
}

// ---------------------------------------------------------------------------
// Merged binB + prep (512-thread heterogeneous blocks):
//   [0, BK)          : bucket CSR build (self-computed base via gcnt scan)
//   [PB_PACK, +16)   : pack L1/L2 [W_rel;W_root] -> MFMA B-frag order (bf16)
//   [PB_GB, +2)      : graph boundaries (binary search over sorted batch)
//   [PB_WF, +5)      : fold layer3+linear -> Wrl/Wro/bfold
//   [PB_CVT, ...)    : x f32 -> bf16
// binB depends only on binA outputs; prep roles depend only on inputs, so
// they run concurrently and fill the machine.
// ---------------------------------------------------------------------------
__global__ __launch_bounds__(512) void k_binbprep(
    const int* __restrict__ gcnt, const int* __restrict__ buck,
    int* __restrict__ rp, int* __restrict__ csr,
    const float* __restrict__ x, u16* __restrict__ xb,
    const float* __restrict__ W1r, const float* __restrict__ W1o,
    const float* __restrict__ W2r, const float* __restrict__ W2o,
    u16* __restrict__ Bp,
    const int* __restrict__ batch, int* __restrict__ gstart,
    const float* __restrict__ W3r, const float* __restrict__ W3o,
    const float* __restrict__ b3, const float* __restrict__ W_lin,
    const float* __restrict__ b_lin,
    float* __restrict__ Wrl, float* __restrict__ Wro, float* __restrict__ bfold) {
    int bid = blockIdx.x;
    int tid = threadIdx.x;

    if (bid < BK) {
        // ---- bucket CSR build ----
        __shared__ int hist[BNW];
        __shared__ int scanbuf[BNW];
        int b = bid;

        scanbuf[tid] = (tid < b) ? gcnt[tid] : 0;
        __syncthreads();
        for (int off = 1; off < BNW; off <<= 1) {
            int t = (tid >= off) ? scanbuf[tid - off] : 0;
            __syncthreads();
            scanbuf[tid] += t;
            __syncthreads();
        }
        int base = scanbuf[BNW - 1];

        int n = gcnt[b];
        if (n > BCAP) n = BCAP;
        const int* bb = buck + (size_t)b * BCAP;

        hist[tid] = 0;
        __syncthreads();
        for (int i = tid; i < n; i += BNW) atomicAdd(&hist[bb[i] & (BNW - 1)], 1);
        __syncthreads();

        int v = hist[tid];
        scanbuf[tid] = v;
        __syncthreads();
        for (int off = 1; off < BNW; off <<= 1) {
            int t = (tid >= off) ? scanbuf[tid - off] : 0;
            __syncthreads();
            scanbuf[tid] += t;
            __syncthreads();
        }
        int excl = scanbuf[tid] - v;
        int node = (b << BSH) + tid;
        if (node < NN) rp[node] = base + excl;
        if (b == 0 && tid == 0) rp[NN] = NE;
        __syncthreads();
        hist[tid] = base + excl;      // cursor
        __syncthreads();
        for (int i = tid; i < n; i += BNW) {
            int en = bb[i];
            int p = atomicAdd(&hist[en & (BNW - 1)], 1);
            csr[p] = en >> BSH;
        }
    } else if (bid < PB_GB) {
        // ---- weight pack (2 layers x 4096 items) ----
        int tt = (bid - PB_PACK) * 512 + tid;     // 0..8191
        int layer = tt >> 12;
        int t = tt & 4095;
        const float* Wr = (layer == 0) ? W1r : W2r;
        const float* Wo = (layer == 0) ? W1o : W2o;
        u16* outp = Bp + layer * 32768;
        int lane = t & 63;
        int nfrag = (t >> 6) & 7;
        int kk = t >> 9;
        int col = nfrag * 16 + (lane & 15);
        int k0 = kk * 32 + (lane >> 4) * 8;
        u16 vals[8];
#pragma unroll
        for (int j = 0; j < 8; ++j) {
            int k = k0 + j;
            float w = (k < C) ? Wr[k * C + col] : Wo[(k - C) * C + col];
            vals[j] = f2bf(w);
        }
        *reinterpret_cast<short8*>(outp + (size_t)t * 8) = *reinterpret_cast<const short8*>(vals);
    } else if (bid < PB_WF) {
        // ---- graph boundaries ----
        int g = (bid - PB_GB) * 512 + tid;
        if (g > NG) return;
        int lo = 0, hi = NN;
        while (lo < hi) { int mid = (lo + hi) >> 1; if (batch[mid] < g) lo = mid + 1; else hi = mid; }
        gstart[g] = lo;
    } else if (bid < PB_CVT) {
        // ---- wfold: 10 outputs x 256 threads = 2560 items ----
        int idx = (bid - PB_WF) * 512 + tid;
        if (idx >= OC * 256) return;
        int o = idx >> 8;
        int sub = idx & 255;
        if (sub < 128) {
            float s = 0.0f;
#pragma unroll 8
            for (int c = 0; c < C; ++c) s += W3r[sub * C + c] * W_lin[c * OC + o];
            Wrl[sub * OC + o] = s;
        } else {
            int k = sub - 128;
            float s = 0.0f;
#pragma unroll 8
            for (int c = 0; c < C; ++c) s += W3o[k * C + c] * W_lin[c * OC + o];
            Wro[k * OC + o] = s;
        }
        if (sub == 0) {
            float s = 0.0f;
            for (int c = 0; c < C; ++c) s += b3[c] * W_lin[c * OC + o];
            bfold[o] = b_lin[o] + s;
        }
    } else {
        // ---- x f32 -> bf16 ----
        int i = (bid - PB_CVT) * 512 + tid;
        size_t base = (size_t)i * 8;
        if (base >= (size_t)NN * C) return;
        float4 a = *reinterpret_cast<const float4*>(x + base);
        float4 b = *reinterpret_cast<const float4*>(x + base + 4);
        u16 o[8] = { f2bf(a.x), f2bf(a.y), f2bf(a.z), f2bf(a.w),
                     f2bf(b.x), f2bf(b.y), f2bf(b.z), f2bf(b.w) };
        *reinterpret_cast<short8*>(xb + base) = *reinterpret_cast<const short8*>(o);
    }
}

// ---------------------------------------------------------------------------
// Gather-aggregate (bf16): agg[i] = sum_{j in in(i)} h[j].
// Whole wave per node: lane = (jj 0..3, seg 0..15); 8 edges/iteration.
// ---------------------------------------------------------------------------
__global__ __launch_bounds__(256) void k_gather(const u16* __restrict__ h,
                                                const int* __restrict__ rp,
                                                const int* __restrict__ csr,
                                                u16* __restrict__ agg) {
    int t = blockIdx.x * blockDim.x + threadIdx.x;
    int node = t >> 6;
    if (node >= NN) return;
    int lane = t & 63;
    int jj = lane >> 4;          // edge slot 0..3
    int seg = (lane & 15) * 8;   // element offset within row
    int beg = rp[node], end = rp[node + 1];

    float acc[8] = {};
    int j0 = beg;
    for (; j0 + 8 <= end; j0 += 8) {
        int sa = csr[j0 + jj];
        int sb = csr[j0 + 4 + jj];
        short8 va = *reinterpret_cast<const short8*>(h + (size_t)sa * C + seg);
        short8 vb = *reinterpret_cast<const short8*>(h + (size_t)sb * C + seg);
#pragma unroll
        for (int q = 0; q < 8; ++q) {
            acc[q] += bf2f((u16)va[q]);
            acc[q] += bf2f((u16)vb[q]);
        }
    }
    if (j0 < end) {
        int ja = j0 + jj;
        int jb = j0 + 4 + jj;
        if (ja < end) {
            int sa = csr[ja];
            short8 va = *reinterpret_cast<const short8*>(h + (size_t)sa * C + seg);
#pragma unroll
            for (int q = 0; q < 8; ++q) acc[q] += bf2f((u16)va[q]);
        }
        if (jb < end) {
            int sb = csr[jb];
            short8 vb = *reinterpret_cast<const short8*>(h + (size_t)sb * C + seg);
#pragma unroll
            for (int q = 0; q < 8; ++q) acc[q] += bf2f((u16)vb[q]);
        }
    }

#pragma unroll
    for (int q = 0; q < 8; ++q) {
        acc[q] += __shfl_xor(acc[q], 32);
        acc[q] += __shfl_xor(acc[q], 16);
    }
    if (lane < 16) {
        u16 o[8];
#pragma unroll
        for (int q = 0; q < 8; ++q) o[q] = f2bf(acc[q]);
        *reinterpret_cast<short8*>(agg + (size_t)node * C + seg) =
            *reinterpret_cast<const short8*>(o);
    }
}

// ---------------------------------------------------------------------------
// MFMA transform: out = [relu]( [agg|h] @ [W_rel;W_root] + b ), bf16 in/out.
// All 8 A-fragments prefetched into registers (8 outstanding HBM loads per
// wave) before the MFMA loop.  LDS-staged coalesced epilogue.  Safe in-place.
// TSUM: accumulate per-graph column sums of the output tile into Tpart.
// ---------------------------------------------------------------------------
template <bool RELU, bool TSUM>
__global__ __launch_bounds__(256) void k_transform_mfma(
    const u16* __restrict__ agg, const u16* __restrict__ h,
    const u16* __restrict__ Bp, const float* __restrict__ bias,
    u16* __restrict__ out,
    const int* __restrict__ batch, float* __restrict__ Tpart) {
    __shared__ u16 tile[4][16 * TSTRIDE];   // 16.9 KB
    int wave = threadIdx.x >> 6;
    int lane = threadIdx.x & 63;
    int row0 = blockIdx.x * 64 + wave * 16;
    int arow = row0 + (lane & 15);
    int rclamp = arow < NN ? arow : NN - 1;
    int koff = (lane >> 4) * 8;

    // prefetch all 8 A-fragments (4 from agg, 4 from h)
    bf16x8 afr[8];
#pragma unroll
    for (int kk = 0; kk < 4; ++kk)
        afr[kk] = *reinterpret_cast<const bf16x8*>(agg + (size_t)rclamp * C + kk * 32 + koff);
#pragma unroll
    for (int kk = 0; kk < 4; ++kk)
        afr[4 + kk] = *reinterpret_cast<const bf16x8*>(h + (size_t)rclamp * C + kk * 32 + koff);

    f32x4 acc[8] = {};
#pragma unroll
    for (int kk = 0; kk < 8; ++kk) {
        const u16* bp = Bp + ((size_t)kk * 8 * 64 + lane) * 8;
#pragma unroll
        for (int n = 0; n < 8; ++n) {
            bf16x8 b = *reinterpret_cast<const bf16x8*>(bp + (size_t)n * 64 * 8);
            acc[n] = __builtin_amdgcn_mfma_f32_16x16x32_bf16(afr[kk], b, acc[n], 0, 0, 0);
        }
    }

    u16* T = tile[wave];
    int colbase = lane & 15;
    int rloc = (lane >> 4) * 4;
#pragma unroll
    for (int n = 0; n < 8; ++n) {
        int col = n * 16 + colbase;
        float bb = bias[col];
#pragma unroll
        for (int r = 0; r < 4; ++r) {
            float v = acc[n][r] + bb;
            if (RELU) v = fmaxf(v, 0.0f);
            T[(rloc + r) * TSTRIDE + col] = f2bf(v);
        }
    }
    __syncthreads();

#pragma unroll
    for (int k = 0; k < 4; ++k) {
        int idx = k * 64 + lane;
        int lr = idx >> 4;
        int off = (idx & 15) * 8;
        int ro = row0 + lr;
        if (ro < NN) {
            short8 v = *reinterpret_cast<const short8*>(&T[lr * TSTRIDE + off]);
            *reinterpret_cast<short8*>(out + (size_t)ro * C + off) = v;
        }
    }

    if (TSUM) {
        if (threadIdx.x < C) {
            int c = threadIdx.x;
            int base = blockIdx.x * 64;
            float run = 0.0f;
            int curg = -1;
            for (int r = 0; r < 64; ++r) {
                int ro = base + r;
                if (ro >= NN) break;
                int g = batch[ro];
                if (g != curg) {
                    if (curg >= 0) atomicAdd(&Tpart[(size_t)curg * C + c], run);
                    run = 0.0f;
                    curg = g;
                }
                run += bf2f(tile[r >> 4][(r & 15) * TSTRIDE + c]);
            }
            if (curg >= 0) atomicAdd(&Tpart[(size_t)curg * C + c], run);
        }
    }
}

// ---------------------------------------------------------------------------
// k_gsum: layer-3 edge sum.  Per graph g (NSPLIT blocks each):
// S_g = sum over its contiguous CSR edge window of h2[src].  ILP-4 loop.
// ---------------------------------------------------------------------------
__global__ __launch_bounds__(256) void k_gsum(
    const u16* __restrict__ h, const int* __restrict__ rp,
    const int* __restrict__ csr, const int* __restrict__ gstart,
    float* __restrict__ partial) {
    int b = blockIdx.x;
    int g = b >> 3;              // NSPLIT = 8
    int p = b & 7;
    int slot = threadIdx.x >> 4; // 0..15
    int seg = (threadIdx.x & 15) * 8;

    int gs = gstart[g], ge = gstart[g + 1];
    int es = rp[gs], ee = rp[ge];
    int m = ee - es;
    int js = es + (int)(((long long)m * p) >> 3);
    int je = es + (int)(((long long)m * (p + 1)) >> 3);

    float acc[8] = {};
    int j = js + slot;
    for (; j + 48 < je; j += 64) {
        int r0 = csr[j];
        int r1 = csr[j + 16];
        int r2 = csr[j + 32];
        int r3 = csr[j + 48];
        short8 v0 = *reinterpret_cast<const short8*>(h + (size_t)r0 * C + seg);
        short8 v1 = *reinterpret_cast<const short8*>(h + (size_t)r1 * C + seg);
        short8 v2 = *reinterpret_cast<const short8*>(h + (size_t)r2 * C + seg);
        short8 v3 = *reinterpret_cast<const short8*>(h + (size_t)r3 * C + seg);
#pragma unroll
        for (int q = 0; q < 8; ++q) {
            acc[q] += bf2f((u16)v0[q]);
            acc[q] += bf2f((u16)v1[q]);
            acc[q] += bf2f((u16)v2[q]);
            acc[q] += bf2f((u16)v3[q]);
        }
    }
    for (; j < je; j += 16) {
        int r0 = csr[j];
        short8 v0 = *reinterpret_cast<const short8*>(h + (size_t)r0 * C + seg);
#pragma unroll
        for (int q = 0; q < 8; ++q) acc[q] += bf2f((u16)v0[q]);
    }

    __shared__ float red[16][C];   // 8 KB
#pragma unroll
    for (int q = 0; q < 8; ++q) red[slot][seg + q] = acc[q];
    __syncthreads();
    if (threadIdx.x < C) {
        float s = 0.0f;
#pragma unroll
        for (int r = 0; r < 16; ++r) s += red[r][threadIdx.x];
        partial[(size_t)b * C + threadIdx.x] = s;
    }
}

// ---------------------------------------------------------------------------
// k_gout: reduce NSPLIT S-partials + read Tpart, then
// out_g = (S@Wrl + T@Wro)/n + bfold.  Grid = NG blocks x 128 threads.
// ---------------------------------------------------------------------------
__global__ __launch_bounds__(128) void k_gout(
    const float* __restrict__ partial, const float* __restrict__ Tpart,
    const int* __restrict__ gstart,
    const float* __restrict__ Wrl, const float* __restrict__ Wro,
    const float* __restrict__ bfold, float* __restrict__ out) {
    int g = blockIdx.x;
    int k = threadIdx.x;
    __shared__ float S[C], T[C];
    float s = 0.0f;
#pragma unroll
    for (int p = 0; p < NSPLIT; ++p)
        s += partial[((size_t)(g * NSPLIT + p)) * C + k];
    S[k] = s;
    T[k] = Tpart[(size_t)g * C + k];
    __syncthreads();
    if (k < OC) {
        int n = gstart[g + 1] - gstart[g];
        float inv = 1.0f / (float)max(n, 1);
        float o = bfold[k];
#pragma unroll 8
        for (int kk = 0; kk < C; ++kk)
            o += (S[kk] * Wrl[kk * OC + k] + T[kk] * Wro[kk * OC + k]) * inv;
        out[g * OC + k] = o;
    }
}

extern "C" void kernel_launch(void* const* d_in, const int* in_sizes, int n_in,
                              void* d_out, int out_size, void* d_ws, size_t ws_size,
                              hipStream_t stream) {
    const float* x       = (const float*)d_in[0];
    const int*   eidx    = (const int*)d_in[1];
    const int*   batch   = (const int*)d_in[2];
    const float* W1_rel  = (const float*)d_in[3];
    const float* b1      = (const float*)d_in[4];
    const float* W1_root = (const float*)d_in[5];
    const float* W2_rel  = (const float*)d_in[6];
    const float* b2      = (const float*)d_in[7];
    const float* W2_root = (const float*)d_in[8];
    const float* W3_rel  = (const float*)d_in[9];
    const float* b3      = (const float*)d_in[10];
    const float* W3_root = (const float*)d_in[11];
    const float* W_lin   = (const float*)d_in[12];
    const float* b_lin   = (const float*)d_in[13];
    float* out = (float*)d_out;

    const int* src = eidx;
    const int* dst = eidx + NE;

    // Workspace layout
    u16* xb   = (u16*)d_ws;                       // NN*C bf16
    u16* hb   = xb + (size_t)NN * C;              // NN*C bf16
    u16* aggb = hb + (size_t)NN * C;              // NN*C bf16
    u16* Bp   = aggb + (size_t)NN * C;            // 2 * 32768 bf16
    int* rp      = (int*)(Bp + 2 * 32768);        // NN+1
    int* csr     = rp + NN + 1;                   // NE
    int* buck    = csr + NE;                      // BK*BCAP
    int* gcnt    = buck + (size_t)BK * BCAP;      // BK        (zeroed together
    float* Tpart = (float*)(gcnt + BK);           // NG*C       with Tpart)
    int* gstart  = (int*)(Tpart + (size_t)NG * C);// NG+1
    float* partial = (float*)(gstart + NG + 2);   // NG*NSPLIT*C
    float* Wrl   = partial + (size_t)NG * NSPLIT * C;    // C*OC
    float* Wro   = Wrl + C * OC;                  // C*OC
    float* bfold = Wro + C * OC;                  // OC

    const int gb = (NN * 64 + 255) / 256;         // gather blocks (64 lanes/node)
    const int tb = (NN + 63) / 64;                // transform blocks (64 rows)

    // ---- Bucketed CSR build phase A ----
    hipMemsetAsync(gcnt, 0, BK * sizeof(int) + (size_t)NG * C * sizeof(float), stream);
    k_binA<<<ABLK, 256, 0, stream>>>(src, dst, gcnt, buck);

    // ---- binB + all precompute, merged & concurrent ----
    k_binbprep<<<PB_TOT, 512, 0, stream>>>(gcnt, buck, rp, csr,
                                           x, xb, W1_rel, W1_root, W2_rel, W2_root,
                                           Bp, batch, gstart,
                                           W3_rel, W3_root, b3, W_lin, b_lin,
                                           Wrl, Wro, bfold);

    // ---- Layer 1 ----
    k_gather<<<gb, 256, 0, stream>>>(xb, rp, csr, aggb);
    k_transform_mfma<true, false><<<tb, 256, 0, stream>>>(aggb, xb, Bp, b1, hb,
                                                          batch, Tpart);

    // ---- Layer 2 (in-place; epilogue accumulates per-graph T sums) ----
    k_gather<<<gb, 256, 0, stream>>>(hb, rp, csr, aggb);
    k_transform_mfma<true, true><<<tb, 256, 0, stream>>>(aggb, hb, Bp + 32768, b2,
                                                         hb, batch, Tpart);

    // ---- Layer 3 + mean-pool + final linear, algebraically collapsed ----
    k_gsum<<<NG * NSPLIT, 256, 0, stream>>>(hb, rp, csr, gstart, partial);
    k_gout<<<NG, 128, 0, stream>>>(partial, Tpart, gstart, Wrl, Wro, bfold, out);
}